// Round 1
// baseline (1494.486 us; speedup 1.0000x reference)
//
#include <hip/hip_runtime.h>
#include <hip/hip_bf16.h>
#include <math.h>

// ---------- types ----------
typedef __bf16 bf16x8 __attribute__((ext_vector_type(8)));
typedef __bf16 bf16x4 __attribute__((ext_vector_type(4)));
typedef float  floatx4 __attribute__((ext_vector_type(4)));

#define D_MODEL 1024
#define SEQ     2048
#define NHEAD   16
#define HD      64

__device__ __forceinline__ void async16(const void* g, void* l) {
  __builtin_amdgcn_global_load_lds((const __attribute__((address_space(1))) void*)g,
                                   (__attribute__((address_space(3))) void*)l, 16, 0, 0);
}

// ---------- weight fp32 -> bf16 convert ----------
__global__ __launch_bounds__(256)
void cvtw_kernel(const float* __restrict__ in, __bf16* __restrict__ out) {
  const size_t i = ((size_t)blockIdx.x * 256 + threadIdx.x) * 4;
  const floatx4 f = *(const floatx4*)(in + i);
  bf16x4 o = { (__bf16)f[0], (__bf16)f[1], (__bf16)f[2], (__bf16)f[3] };
  *(bf16x4*)(out + i) = o;
}

// ---------- LayerNorm: fp32 row(1024) -> bf16 (or fp32 for final) ----------
template<bool OUT_BF16>
__global__ __launch_bounds__(256)
void ln_kernel(const float* __restrict__ x, const float* __restrict__ w,
               const float* __restrict__ b, void* __restrict__ out)
{
  const int row = blockIdx.x;
  const int tid = threadIdx.x;
  const floatx4 f = *(const floatx4*)(x + (size_t)row * D_MODEL + tid * 4);
  float s = f[0] + f[1] + f[2] + f[3];
  #pragma unroll
  for (int off = 1; off < 64; off <<= 1) s += __shfl_xor(s, off);
  __shared__ float red[8];
  const int wv = tid >> 6;
  if ((tid & 63) == 0) red[wv] = s;
  __syncthreads();
  const float mu = (red[0] + red[1] + red[2] + red[3]) * (1.0f / 1024.0f);
  float d0 = f[0] - mu, d1 = f[1] - mu, d2 = f[2] - mu, d3 = f[3] - mu;
  float ss = d0 * d0 + d1 * d1 + d2 * d2 + d3 * d3;
  #pragma unroll
  for (int off = 1; off < 64; off <<= 1) ss += __shfl_xor(ss, off);
  if ((tid & 63) == 0) red[4 + wv] = ss;
  __syncthreads();
  const float rstd = rsqrtf((red[4] + red[5] + red[6] + red[7]) * (1.0f / 1024.0f) + 1e-5f);
  const floatx4 wv4 = *(const floatx4*)(w + tid * 4);
  const floatx4 bv4 = *(const floatx4*)(b + tid * 4);
  const float y0 = d0 * rstd * wv4[0] + bv4[0];
  const float y1 = d1 * rstd * wv4[1] + bv4[1];
  const float y2 = d2 * rstd * wv4[2] + bv4[2];
  const float y3 = d3 * rstd * wv4[3] + bv4[3];
  if (OUT_BF16) {
    bf16x4 o = { (__bf16)y0, (__bf16)y1, (__bf16)y2, (__bf16)y3 };
    *(bf16x4*)((__bf16*)out + (size_t)row * D_MODEL + tid * 4) = o;
  } else {
    floatx4 o = { y0, y1, y2, y3 };
    *(floatx4*)((float*)out + (size_t)row * D_MODEL + tid * 4) = o;
  }
}

#define EPI_GELU 1
#define EPI_RES  2
#define EPI_QKV  3

// ---------- GEMM256: 256x256 tile, BK=64, 8 waves, 4-phase counted-vmcnt pipeline ----------
// T2 (XOR swizzle, source-side pre-swizzle per rule #21) + T3/T4 (phase split, vmcnt(6),
// never drain-0 in loop) + T5 (setprio around MFMA cluster).
// Stage order per K-tile: q0=A-quarter0, q1=B-quarter0, q2=B-quarter1, q3=A-quarter1.
// Quadrant reads: q0:(A0,B0) q1:(A0,B1) q2:(A1,B0) q3:(A1,B1).
// vmcnt(6) at q0/q1/q2 certifies exactly the quarter first read in that phase
// (allow 3 newest quarter-tiles = 6 loads in flight; queue is FIFO per m135).
__device__ __forceinline__ void stage_q(int q, const __bf16* Ab, const __bf16* Wb,
                                        int K, int k0,
                                        __bf16 (*As)[64], __bf16 (*Bs)[64], int tid)
{
  #pragma unroll
  for (int j = 0; j < 2; ++j) {
    const int ch = j * 512 + tid;        // 0..1023 chunks of 16B (one quarter-tile)
    const int rq = ch >> 3, c16 = ch & 7;
    if (q == 0 || q == 3) {              // A quarter mh: rows {mh*64..+63} U {128+mh*64..+63}
      const int mh = (q == 3) ? 1 : 0;
      const int row = (rq & 63) + ((rq >> 6) << 7) + mh * 64;
      const int gc = (c16 ^ (row & 7)) * 8;          // pre-swizzled global column
      async16(Ab + (size_t)row * K + k0 + gc, &As[row][c16 * 8]);
    } else {                              // B quarter nh: rows where (row>>5)&1 == nh
      const int nh = (q == 2) ? 1 : 0;
      const int row = (rq & 31) + ((rq >> 5) << 6) + nh * 32;
      const int gc = (c16 ^ (row & 7)) * 8;
      async16(Wb + (size_t)row * K + k0 + gc, &Bs[row][c16 * 8]);
    }
  }
}

template<int MODE>
__global__ __launch_bounds__(512, 2)
void gemm256_kernel(const __bf16* __restrict__ A, const __bf16* __restrict__ W,
                    const float* __restrict__ bias, void* out,
                    __bf16* __restrict__ vT, int M, int N, int K)
{
  __shared__ __align__(16) __bf16 As[2][256][64];   // 64 KiB (double-buffered A tile)
  __shared__ __align__(16) __bf16 Bs[2][256][64];   // 64 KiB
  const int tid = threadIdx.x;
  const int lane = tid & 63, wv = tid >> 6;
  const int wr = wv >> 2, wc = wv & 3;              // 2 x 4 wave grid
  const int quad = lane >> 4, r = lane & 15;
  const int sw = r & 7;
  const int m0 = blockIdx.x * 256, n0 = blockIdx.y * 256;
  const __bf16* Ab = A + (size_t)m0 * K;
  const __bf16* Wb = W + (size_t)n0 * K;

  floatx4 acc[8][4] = {};                           // 128x64 per wave

  const int nt = K >> 6;
  // prologue: tile 0 -> buf 0 (order A0,B0,B1,A1 = the certification order)
  stage_q(0, Ab, Wb, K, 0, As[0], Bs[0], tid);
  stage_q(1, Ab, Wb, K, 0, As[0], Bs[0], tid);
  stage_q(2, Ab, Wb, K, 0, As[0], Bs[0], tid);
  stage_q(3, Ab, Wb, K, 0, As[0], Bs[0], tid);

  for (int t = 0; t < nt; ++t) {
    const int p = t & 1;
    // wrap-stage tile 0 on the last iteration: keeps vmcnt counts uniform, data never read
    const int kn = (t + 1 < nt) ? ((t + 1) << 6) : 0;
    __bf16 (*Asr)[64] = As[p];
    __bf16 (*Bsr)[64] = Bs[p];
    __bf16 (*Asw)[64] = As[p ^ 1];
    __bf16 (*Bsw)[64] = Bs[p ^ 1];
    #pragma unroll
    for (int q = 0; q < 4; ++q) {
      stage_q(q, Ab, Wb, K, kn, Asw, Bsw, tid);
      if (q < 3) asm volatile("s_waitcnt vmcnt(6)" ::: "memory");
      __builtin_amdgcn_s_barrier();
      asm volatile("" ::: "memory");
      const int mh = q >> 1, nh = q & 1;
      __builtin_amdgcn_s_setprio(1);
      #pragma unroll
      for (int kk = 0; kk < 2; ++kk) {
        const int cc = ((kk * 4 + quad) ^ sw) * 8;   // swizzled read column
        bf16x8 av[4], bv[2];
        #pragma unroll
        for (int mi = 0; mi < 4; ++mi)
          av[mi] = *(const bf16x8*)&Asr[wr * 128 + mh * 64 + mi * 16 + r][cc];
        #pragma unroll
        for (int ni = 0; ni < 2; ++ni)
          bv[ni] = *(const bf16x8*)&Bsr[wc * 64 + nh * 32 + ni * 16 + r][cc];
        #pragma unroll
        for (int ni = 0; ni < 2; ++ni)
          #pragma unroll
          for (int mi = 0; mi < 4; ++mi)
            acc[mh * 4 + mi][nh * 2 + ni] = __builtin_amdgcn_mfma_f32_16x16x32_bf16(
                av[mi], bv[ni], acc[mh * 4 + mi][nh * 2 + ni], 0, 0, 0);
      }
      __builtin_amdgcn_s_setprio(0);
      asm volatile("" ::: "memory");
      __builtin_amdgcn_s_barrier();   // iteration-closing barrier fences buffer reuse
    }
  }
  asm volatile("s_waitcnt vmcnt(0)" ::: "memory");   // drain wrap-stage before endpgm

  // epilogue: C/D layout col=lane&15, row=quad*4+reg (verified convention)
  #pragma unroll
  for (int ni = 0; ni < 4; ++ni) {
    const int nn = n0 + wc * 64 + ni * 16 + r;
    const float bvv = bias[nn];
    #pragma unroll
    for (int mi = 0; mi < 8; ++mi) {
      #pragma unroll
      for (int v = 0; v < 4; ++v) {
        const int mm = m0 + wr * 128 + mi * 16 + quad * 4 + v;
        float val = acc[mi][ni][v] + bvv;
        if (MODE == EPI_GELU) {
          val = 0.5f * val * (1.0f + erff(val * 0.70710678118654752f));
          ((__bf16*)out)[(size_t)mm * N + nn] = (__bf16)val;
        } else if (MODE == EPI_QKV) {
          if (nn < 2048) {
            const float sv = (nn < 1024) ? val * 0.125f : val;  // fold 1/sqrt(HD) into Q
            ((__bf16*)out)[(size_t)mm * 2048 + nn] = (__bf16)sv;
          } else {
            const int c = nn - 2048, hh = c >> 6, dd = c & 63;
            const int bb = mm >> 11, tt = mm & 2047;
            vT[(size_t)((bb * 16 + hh) * 64 + dd) * 2048 + tt] = (__bf16)val;
          }
        }
      }
    }
  }
}

// ---------- GEMM64 (bf16 W): 128x64 tile, BK=64, EPI_RES; k-halves split ----------
__global__ __launch_bounds__(256, 2)
void gemm64_kernel(const __bf16* __restrict__ A, const __bf16* __restrict__ W,
                   const float* __restrict__ bias, float* __restrict__ out,
                   const float* __restrict__ res, int M, int N, int K)
{
  __shared__ __align__(16) __bf16 As0[128][32], As1[128][32];  // 16 KB
  __shared__ __align__(16) __bf16 Ws0[64][32],  Ws1[64][32];   //  8 KB
  const int tid = threadIdx.x;
  const int lane = tid & 63, w = tid >> 6;
  const int wr = w >> 1, wc = w & 1;
  const int quad = lane >> 4, r = lane & 15;
  const int m0 = blockIdx.x * 128, n0 = blockIdx.y * 64;

  floatx4 acc[4][2] = {};

  const __bf16* Ab = A + (size_t)m0 * K;
  const __bf16* Wb = W + (size_t)n0 * K;
  const int sr = tid >> 2, sc = (tid & 3) * 8;

  for (int k0 = 0; k0 < K; k0 += 64) {
    async16(Ab + (size_t)sr * K + k0 + sc,             &As0[sr][sc]);
    async16(Ab + (size_t)(sr + 64) * K + k0 + sc,      &As0[sr + 64][sc]);
    async16(Ab + (size_t)sr * K + k0 + 32 + sc,        &As1[sr][sc]);
    async16(Ab + (size_t)(sr + 64) * K + k0 + 32 + sc, &As1[sr + 64][sc]);
    async16(Wb + (size_t)sr * K + k0 + sc,             &Ws0[sr][sc]);
    async16(Wb + (size_t)sr * K + k0 + 32 + sc,        &Ws1[sr][sc]);
    __syncthreads();
    bf16x8 af0[4], af1[4];
    #pragma unroll
    for (int mi = 0; mi < 4; ++mi) {
      af0[mi] = *(const bf16x8*)&As0[wr * 64 + mi * 16 + r][quad * 8];
      af1[mi] = *(const bf16x8*)&As1[wr * 64 + mi * 16 + r][quad * 8];
    }
    #pragma unroll
    for (int ni = 0; ni < 2; ++ni) {
      const bf16x8 b0 = *(const bf16x8*)&Ws0[wc * 32 + ni * 16 + r][quad * 8];
      const bf16x8 b1 = *(const bf16x8*)&Ws1[wc * 32 + ni * 16 + r][quad * 8];
      #pragma unroll
      for (int mi = 0; mi < 4; ++mi) {
        acc[mi][ni] = __builtin_amdgcn_mfma_f32_16x16x32_bf16(af0[mi], b0, acc[mi][ni], 0, 0, 0);
        acc[mi][ni] = __builtin_amdgcn_mfma_f32_16x16x32_bf16(af1[mi], b1, acc[mi][ni], 0, 0, 0);
      }
    }
    __syncthreads();
  }

  #pragma unroll
  for (int ni = 0; ni < 2; ++ni) {
    const int nn = n0 + wc * 32 + ni * 16 + r;
    const float bv = bias[nn];
    #pragma unroll
    for (int mi = 0; mi < 4; ++mi) {
      #pragma unroll
      for (int v = 0; v < 4; ++v) {
        const int mm = m0 + wr * 64 + mi * 16 + quad * 4 + v;
        out[(size_t)mm * N + nn] = res[(size_t)mm * N + nn] + acc[mi][ni][v] + bv;
      }
    }
  }
}

// ---------- LEGACY GEMM (fp32 W) — fallback if workspace too small ----------
template<int MODE, int NT>
__global__ __launch_bounds__(256, 2)
void gemm_legacy_kernel(const __bf16* __restrict__ A, const float* __restrict__ W,
                        const float* __restrict__ bias, void* out,
                        const float* __restrict__ res, __bf16* __restrict__ vT,
                        int M, int N, int K)
{
  __shared__ __align__(16) __bf16 As[128][32];
  __shared__ __align__(16) __bf16 Ws[NT][32];
  const int tid = threadIdx.x;
  const int lane = tid & 63, w = tid >> 6;
  const int wr = w >> 1, wc = w & 1;
  const int quad = lane >> 4, r = lane & 15;
  constexpr int NACC = NT / 32;
  const int m0 = blockIdx.x * 128, n0 = blockIdx.y * NT;
  floatx4 acc[4][NACC] = {};
  const __bf16* Ab = A + (size_t)m0 * K;
  const float*  Wb = W + (size_t)n0 * K;
  const int arow = tid >> 2, ac = (tid & 3) * 8;
  const int wrow = tid >> 3, wc4 = (tid & 7) * 4;
  for (int k0 = 0; k0 < K; k0 += 32) {
    async16(Ab + (size_t)arow * K + k0 + ac, &As[arow][ac]);
    async16(Ab + (size_t)(arow + 64) * K + k0 + ac, &As[arow + 64][ac]);
    #pragma unroll
    for (int i = 0; i < NT / 32; ++i) {
      const int rw = wrow + 32 * i;
      const floatx4 f = *(const floatx4*)(Wb + (size_t)rw * K + k0 + wc4);
      bf16x4 h4 = { (__bf16)f[0], (__bf16)f[1], (__bf16)f[2], (__bf16)f[3] };
      *(bf16x4*)&Ws[rw][wc4] = h4;
    }
    __syncthreads();
    bf16x8 af[4];
    #pragma unroll
    for (int mi = 0; mi < 4; ++mi)
      af[mi] = *(const bf16x8*)&As[wr * 64 + mi * 16 + r][quad * 8];
    #pragma unroll
    for (int ni = 0; ni < NACC; ++ni) {
      bf16x8 bf = *(const bf16x8*)&Ws[wc * (NT / 2) + ni * 16 + r][quad * 8];
      #pragma unroll
      for (int mi = 0; mi < 4; ++mi)
        acc[mi][ni] = __builtin_amdgcn_mfma_f32_16x16x32_bf16(af[mi], bf, acc[mi][ni], 0, 0, 0);
    }
    __syncthreads();
  }
  #pragma unroll
  for (int ni = 0; ni < NACC; ++ni) {
    const int nn = n0 + wc * (NT / 2) + ni * 16 + r;
    const float bv = bias[nn];
    #pragma unroll
    for (int mi = 0; mi < 4; ++mi) {
      #pragma unroll
      for (int v = 0; v < 4; ++v) {
        const int mm = m0 + wr * 64 + mi * 16 + quad * 4 + v;
        float val = acc[mi][ni][v] + bv;
        if (MODE == EPI_GELU) {
          val = 0.5f * val * (1.0f + erff(val * 0.70710678118654752f));
          ((__bf16*)out)[(size_t)mm * N + nn] = (__bf16)val;
        } else if (MODE == EPI_RES) {
          ((float*)out)[(size_t)mm * N + nn] = res[(size_t)mm * N + nn] + val;
        } else if (MODE == EPI_QKV) {
          if (nn < 2048) {
            const float sv = (nn < 1024) ? val * 0.125f : val;
            ((__bf16*)out)[(size_t)mm * 2048 + nn] = (__bf16)sv;
          } else {
            const int c = nn - 2048, hh = c >> 6, dd = c & 63;
            const int bb = mm >> 11, t = mm & 2047;
            vT[(size_t)((bb * 16 + hh) * 64 + dd) * 2048 + t] = (__bf16)val;
          }
        }
      }
    }
  }
}

// ---------- Flash attention, transposed-MFMA formulation, 64-key tiles ----------
__global__ __launch_bounds__(256, 4)
void attn_kernel(const __bf16* __restrict__ qk,  // [B*T][2048]: cols 0..1023 Q(*0.125), 1024..2047 K
                 const __bf16* __restrict__ vT,  // [(b*16+h)*64+d][2048]
                 __bf16* __restrict__ out)       // [B*T][1024]
{
  __shared__ __align__(16) __bf16 Qs[2][64][32];
  __shared__ __align__(16) __bf16 Ks[2][64][32];
  __shared__ __align__(16) __bf16 Vs[2][64][32];
  __shared__ __align__(16) __bf16 Ps[4][2][16][32];
  const int tid = threadIdx.x, lane = tid & 63, w = tid >> 6;
  const int quad = lane >> 4, r = lane & 15;
  const int bh = blockIdx.x, b = bh >> 4, h = bh & 15;
  const int yk = blockIdx.y >> 3, yj = blockIdx.y & 7;
  const int qt = (yk << 3) | ((yk & 1) ? (7 - yj) : yj);
  const int q0 = qt * 64;

  {
    const __bf16* qb = qk + ((size_t)(b * SEQ + q0)) * 2048 + h * 64;
    #pragma unroll
    for (int rd = 0; rd < 2; ++rd) {
      const int c = rd * 256 + tid, half = c >> 8, row = (c >> 2) & 63, c8 = (c & 3) * 8;
      async16(qb + (size_t)row * 2048 + half * 32 + c8, &Qs[half][row][c8]);
    }
  }
  __syncthreads();
  const bf16x8 qf0 = *(const bf16x8*)&Qs[0][w * 16 + r][quad * 8];
  const bf16x8 qf1 = *(const bf16x8*)&Qs[1][w * 16 + r][quad * 8];

  const int q = q0 + w * 16 + r;
  float m_i = -INFINITY, l_i = 0.0f;
  floatx4 ot[4] = {};
  const float slope = exp2f(-0.5f * (float)(h + 1));
  const float sq = slope * (float)q;

  const __bf16* kb0 = qk + ((size_t)(b * SEQ)) * 2048 + 1024 + h * 64;
  const __bf16* vb0 = vT + ((size_t)(bh * 64)) * 2048;

  for (int kt = 0; kt <= qt; ++kt) {
    const int kbase = kt << 6;
    #pragma unroll
    for (int rd = 0; rd < 2; ++rd) {
      const int c = rd * 256 + tid, half = c >> 8, row = (c >> 2) & 63, c8 = (c & 3) * 8;
      async16(kb0 + (size_t)(kbase + row) * 2048 + half * 32 + c8, &Ks[half][row][c8]);
    }
    #pragma unroll
    for (int rd = 0; rd < 2; ++rd) {
      const int c = rd * 256 + tid, kb = c >> 8, d = (c >> 2) & 63, c8 = (c & 3) * 8;
      async16(vb0 + (size_t)d * 2048 + kbase + kb * 32 + c8, &Vs[kb][d][c8]);
    }
    __syncthreads();

    floatx4 st[4];
    #pragma unroll
    for (int t = 0; t < 4; ++t) {
      floatx4 z = { 0.0f, 0.0f, 0.0f, 0.0f };
      const bf16x8 kf0 = *(const bf16x8*)&Ks[0][t * 16 + r][quad * 8];
      const bf16x8 kf1 = *(const bf16x8*)&Ks[1][t * 16 + r][quad * 8];
      z = __builtin_amdgcn_mfma_f32_16x16x32_bf16(kf0, qf0, z, 0, 0, 0);
      st[t] = __builtin_amdgcn_mfma_f32_16x16x32_bf16(kf1, qf1, z, 0, 0, 0);
    }
    float mloc = -INFINITY;
    if (kt == qt) {
      #pragma unroll
      for (int t = 0; t < 4; ++t)
        #pragma unroll
        for (int v = 0; v < 4; ++v) {
          const int key = kbase + t * 16 + quad * 4 + v;
          float sv = st[t][v] + slope * (float)key - sq;
          sv = (key <= q) ? sv : -INFINITY;
          st[t][v] = sv;
          mloc = fmaxf(mloc, sv);
        }
    } else {
      #pragma unroll
      for (int t = 0; t < 4; ++t)
        #pragma unroll
        for (int v = 0; v < 4; ++v) {
          const int key = kbase + t * 16 + quad * 4 + v;
          const float sv = st[t][v] + slope * (float)key - sq;
          st[t][v] = sv;
          mloc = fmaxf(mloc, sv);
        }
    }
    mloc = fmaxf(mloc, __shfl_xor(mloc, 16));
    mloc = fmaxf(mloc, __shfl_xor(mloc, 32));
    const float mn = fmaxf(m_i, mloc);
    const float alpha = __expf(m_i - mn);
    m_i = mn;
    float rsum = 0.0f;
    #pragma unroll
    for (int t = 0; t < 4; ++t) {
      bf16x4 p4;
      #pragma unroll
      for (int v = 0; v < 4; ++v) {
        const float p = __expf(st[t][v] - mn);
        rsum += p;
        p4[v] = (__bf16)p;
      }
      *(bf16x4*)&Ps[w][t >> 1][r][(t & 1) * 16 + quad * 4] = p4;
    }
    rsum += __shfl_xor(rsum, 16);
    rsum += __shfl_xor(rsum, 32);
    l_i = l_i * alpha + rsum;
    #pragma unroll
    for (int dt = 0; dt < 4; ++dt) ot[dt] *= alpha;

    #pragma unroll
    for (int kb = 0; kb < 2; ++kb) {
      const bf16x8 pf = *(const bf16x8*)&Ps[w][kb][r][quad * 8];
      #pragma unroll
      for (int dt = 0; dt < 4; ++dt) {
        const bf16x8 vf = *(const bf16x8*)&Vs[kb][dt * 16 + r][quad * 8];
        ot[dt] = __builtin_amdgcn_mfma_f32_16x16x32_bf16(vf, pf, ot[dt], 0, 0, 0);
      }
    }
    __syncthreads();
  }

  const float linv = 1.0f / l_i;
  __bf16* ob = out + (size_t)(b * SEQ + q) * D_MODEL + h * 64;
  #pragma unroll
  for (int dt = 0; dt < 4; ++dt) {
    bf16x4 o4 = { (__bf16)(ot[dt][0] * linv), (__bf16)(ot[dt][1] * linv),
                  (__bf16)(ot[dt][2] * linv), (__bf16)(ot[dt][3] * linv) };
    *(bf16x4*)(ob + dt * 16 + quad * 4) = o4;
  }
}

// ---------- driver ----------
extern "C" void kernel_launch(void* const* d_in, const int* in_sizes, int n_in,
                              void* d_out, int out_size, void* d_ws, size_t ws_size,
                              hipStream_t stream)
{
  (void)in_sizes; (void)n_in; (void)out_size;
  const float* x    = (const float*)d_in[0];
  const float* inW  = (const float*)d_in[1];
  const float* inB  = (const float*)d_in[2];
  const float* outW = (const float*)d_in[3];
  const float* outB = (const float*)d_in[4];
  const float* f1W  = (const float*)d_in[5];
  const float* f1B  = (const float*)d_in[6];
  const float* f2W  = (const float*)d_in[7];
  const float* f2B  = (const float*)d_in[8];
  const float* ln1W = (const float*)d_in[9];
  const float* ln1B = (const float*)d_in[10];
  const float* ln2W = (const float*)d_in[11];
  const float* ln2B = (const float*)d_in[12];
  const float* fnW  = (const float*)d_in[13];
  const float* fnB  = (const float*)d_in[14];

  char* ws = (char*)d_ws;
  float*  x_cur = (float*)(ws);                    // 16.78 MB fp32 residual
  __bf16* xn    = (__bf16*)(ws + 16777216);        //  8.39 MB
  __bf16* qk    = (__bf16*)(ws + 25165824);        // 16.78 MB
  __bf16* vT    = (__bf16*)(ws + 41943040);        //  8.39 MB
  __bf16* attn  = (__bf16*)(ws + 50331648);        //  8.39 MB
  __bf16* hbuf  = (__bf16*)(ws + 25165824);        // 33.55 MB, aliases qk/vT/attn (dead by FFN1)
  // bf16 weight cache (one-time convert per launch)
  __bf16* inWb  = (__bf16*)(ws + 58720256);        // 25.17 MB
  __bf16* outWb = (__bf16*)(ws + 83886080);        //  8.39 MB
  __bf16* f1Wb  = (__bf16*)(ws + 92274688);        // 33.55 MB
  __bf16* f2Wb  = (__bf16*)(ws + 125829120);       // 33.55 MB -> need 159,383,552 B
  const bool bf16w = ws_size >= (size_t)159383552;

  hipMemcpyAsync(x_cur, x, (size_t)16777216, hipMemcpyDeviceToDevice, stream);

  if (bf16w) {
    cvtw_kernel<<<dim3(12288), dim3(256), 0, stream>>>(inW,  inWb);
    cvtw_kernel<<<dim3(4096),  dim3(256), 0, stream>>>(outW, outWb);
    cvtw_kernel<<<dim3(16384), dim3(256), 0, stream>>>(f1W,  f1Wb);
    cvtw_kernel<<<dim3(16384), dim3(256), 0, stream>>>(f2W,  f2Wb);
  }

  for (int i = 0; i < 4; ++i) {
    ln_kernel<true><<<dim3(4096), dim3(256), 0, stream>>>(
        x_cur, ln1W + i * 1024, ln1B + i * 1024, xn);
    if (bf16w)
      gemm256_kernel<EPI_QKV><<<dim3(16, 12), dim3(512), 0, stream>>>(
          xn, inWb + (size_t)i * 3072 * 1024, inB + (size_t)i * 3072,
          qk, vT, 4096, 3072, 1024);
    else
      gemm_legacy_kernel<EPI_QKV, 128><<<dim3(32, 24), dim3(256), 0, stream>>>(
          xn, inW + (size_t)i * 3072 * 1024, inB + (size_t)i * 3072,
          qk, nullptr, vT, 4096, 3072, 1024);
    attn_kernel<<<dim3(32, 32), dim3(256), 0, stream>>>(qk, vT, attn);
    if (bf16w)
      gemm64_kernel<<<dim3(32, 16), dim3(256), 0, stream>>>(
          attn, outWb + (size_t)i * 1024 * 1024, outB + (size_t)i * 1024,
          x_cur, x_cur, 4096, 1024, 1024);
    else
      gemm_legacy_kernel<EPI_RES, 64><<<dim3(32, 16), dim3(256), 0, stream>>>(
          attn, outW + (size_t)i * 1024 * 1024, outB + (size_t)i * 1024,
          x_cur, x_cur, nullptr, 4096, 1024, 1024);
    ln_kernel<true><<<dim3(4096), dim3(256), 0, stream>>>(
        x_cur, ln2W + i * 1024, ln2B + i * 1024, xn);
    if (bf16w)
      gemm256_kernel<EPI_GELU><<<dim3(16, 16), dim3(512), 0, stream>>>(
          xn, f1Wb + (size_t)i * 4096 * 1024, f1B + (size_t)i * 4096,
          hbuf, nullptr, 4096, 4096, 1024);
    else
      gemm_legacy_kernel<EPI_GELU, 128><<<dim3(32, 32), dim3(256), 0, stream>>>(
          xn, f1W + (size_t)i * 4096 * 1024, f1B + (size_t)i * 4096,
          hbuf, nullptr, nullptr, 4096, 4096, 1024);
    if (bf16w)
      gemm64_kernel<<<dim3(32, 16), dim3(256), 0, stream>>>(
          hbuf, f2Wb + (size_t)i * 1024 * 4096, f2B + (size_t)i * 1024,
          x_cur, x_cur, 4096, 1024, 4096);
    else
      gemm_legacy_kernel<EPI_RES, 64><<<dim3(32, 16), dim3(256), 0, stream>>>(
          hbuf, f2W + (size_t)i * 1024 * 4096, f2B + (size_t)i * 1024,
          x_cur, x_cur, nullptr, 4096, 1024, 4096);
  }
  ln_kernel<false><<<dim3(4096), dim3(256), 0, stream>>>(x_cur, fnW, fnB, d_out);
}

// Round 3
// 1349.524 us; speedup vs baseline: 1.1074x; 1.1074x over previous
//
#include <hip/hip_runtime.h>
#include <hip/hip_bf16.h>
#include <math.h>

// ---------- types ----------
typedef __bf16 bf16x8 __attribute__((ext_vector_type(8)));
typedef __bf16 bf16x4 __attribute__((ext_vector_type(4)));
typedef float  floatx4 __attribute__((ext_vector_type(4)));

#define D_MODEL 1024
#define SEQ     2048
#define NHEAD   16
#define HD      64

__device__ __forceinline__ void async16(const void* g, void* l) {
  __builtin_amdgcn_global_load_lds((const __attribute__((address_space(1))) void*)g,
                                   (__attribute__((address_space(3))) void*)l, 16, 0, 0);
}

// ---------- weight fp32 -> bf16 convert ----------
__global__ __launch_bounds__(256)
void cvtw_kernel(const float* __restrict__ in, __bf16* __restrict__ out) {
  const size_t i = ((size_t)blockIdx.x * 256 + threadIdx.x) * 4;
  const floatx4 f = *(const floatx4*)(in + i);
  bf16x4 o = { (__bf16)f[0], (__bf16)f[1], (__bf16)f[2], (__bf16)f[3] };
  *(bf16x4*)(out + i) = o;
}

// ---------- LayerNorm: fp32 row(1024) -> bf16 (or fp32 for final) ----------
template<bool OUT_BF16>
__global__ __launch_bounds__(256)
void ln_kernel(const float* __restrict__ x, const float* __restrict__ w,
               const float* __restrict__ b, void* __restrict__ out)
{
  const int row = blockIdx.x;
  const int tid = threadIdx.x;
  const floatx4 f = *(const floatx4*)(x + (size_t)row * D_MODEL + tid * 4);
  float s = f[0] + f[1] + f[2] + f[3];
  #pragma unroll
  for (int off = 1; off < 64; off <<= 1) s += __shfl_xor(s, off);
  __shared__ float red[8];
  const int wv = tid >> 6;
  if ((tid & 63) == 0) red[wv] = s;
  __syncthreads();
  const float mu = (red[0] + red[1] + red[2] + red[3]) * (1.0f / 1024.0f);
  float d0 = f[0] - mu, d1 = f[1] - mu, d2 = f[2] - mu, d3 = f[3] - mu;
  float ss = d0 * d0 + d1 * d1 + d2 * d2 + d3 * d3;
  #pragma unroll
  for (int off = 1; off < 64; off <<= 1) ss += __shfl_xor(ss, off);
  if ((tid & 63) == 0) red[4 + wv] = ss;
  __syncthreads();
  const float rstd = rsqrtf((red[4] + red[5] + red[6] + red[7]) * (1.0f / 1024.0f) + 1e-5f);
  const floatx4 wv4 = *(const floatx4*)(w + tid * 4);
  const floatx4 bv4 = *(const floatx4*)(b + tid * 4);
  const float y0 = d0 * rstd * wv4[0] + bv4[0];
  const float y1 = d1 * rstd * wv4[1] + bv4[1];
  const float y2 = d2 * rstd * wv4[2] + bv4[2];
  const float y3 = d3 * rstd * wv4[3] + bv4[3];
  if (OUT_BF16) {
    bf16x4 o = { (__bf16)y0, (__bf16)y1, (__bf16)y2, (__bf16)y3 };
    *(bf16x4*)((__bf16*)out + (size_t)row * D_MODEL + tid * 4) = o;
  } else {
    floatx4 o = { y0, y1, y2, y3 };
    *(floatx4*)((float*)out + (size_t)row * D_MODEL + tid * 4) = o;
  }
}

#define EPI_GELU 1
#define EPI_RES  2
#define EPI_QKV  3

// ---------- GEMM256: 256x256 tile, BK=64, 8 waves, 1-phase/K-tile counted-vmcnt ----------
// T2 swizzle (pre-swizzled global source per rule #21, XOR on read), T4 counted vmcnt(8)
// with a full-iteration issue-to-wait distance (> HBM latency), T5 setprio.
// Per K-tile per wave: 24 ds_read_b128 (8 A + 4 B per kk-slice) feed 64 MFMA (1:2.67),
// half the LDS traffic of the 4-phase quadrant version. 2 barriers per K-tile.
__device__ __forceinline__ void stage_tile(const __bf16* Ab, const __bf16* Wb,
                                           int K, int k0,
                                           __bf16 (*As)[64], __bf16 (*Bs)[64], int tid)
{
  #pragma unroll
  for (int j = 0; j < 4; ++j) {
    const int ch = j * 512 + tid;                  // 0..2047: A-tile 16B chunks
    const int row = ch >> 3, c16 = ch & 7;
    const int gc = (c16 ^ (row & 7)) * 8;          // pre-swizzled global column
    async16(Ab + (size_t)row * K + k0 + gc, &As[row][c16 * 8]);
  }
  #pragma unroll
  for (int j = 0; j < 4; ++j) {
    const int ch = j * 512 + tid;                  // 0..2047: B-tile 16B chunks
    const int row = ch >> 3, c16 = ch & 7;
    const int gc = (c16 ^ (row & 7)) * 8;
    async16(Wb + (size_t)row * K + k0 + gc, &Bs[row][c16 * 8]);
  }
}

template<int MODE>
__global__ __launch_bounds__(512, 2)
void gemm256_kernel(const __bf16* __restrict__ A, const __bf16* __restrict__ W,
                    const float* __restrict__ bias, void* out,
                    __bf16* __restrict__ vT, int M, int N, int K)
{
  __shared__ __align__(16) __bf16 As[2][256][64];   // 64 KiB (double-buffered A tile)
  __shared__ __align__(16) __bf16 Bs[2][256][64];   // 64 KiB
  const int tid = threadIdx.x;
  const int lane = tid & 63, wv = tid >> 6;
  const int wr = wv >> 2, wc = wv & 3;              // 2 x 4 wave grid
  const int quad = lane >> 4, r = lane & 15;
  const int sw = r & 7;
  const int m0 = blockIdx.x * 256, n0 = blockIdx.y * 256;
  const __bf16* Ab = A + (size_t)m0 * K;
  const __bf16* Wb = W + (size_t)n0 * K;

  floatx4 acc[8][4] = {};                           // 128x64 per wave

  const int nt = K >> 6;
  stage_tile(Ab, Wb, K, 0, As[0], Bs[0], tid);      // prologue: tile 0 -> buf 0

  for (int t = 0; t < nt; ++t) {
    const int p = t & 1;
    // wrap-stage tile 0 on the last iteration: keeps vmcnt counts uniform, data never read
    const int kn = (t + 1 < nt) ? ((t + 1) << 6) : 0;
    stage_tile(Ab, Wb, K, kn, As[p ^ 1], Bs[p ^ 1], tid);   // 8 loads -> 16 outstanding
    asm volatile("s_waitcnt vmcnt(8)" ::: "memory");        // certify tile t (issued 1 iter ago)
    __builtin_amdgcn_s_barrier();                           // all waves' contributions landed
    asm volatile("" ::: "memory");
    __bf16 (*Asr)[64] = As[p];
    __bf16 (*Bsr)[64] = Bs[p];
    #pragma unroll
    for (int kk = 0; kk < 2; ++kk) {
      const int cc = ((kk * 4 + quad) ^ sw) * 8;   // swizzled read column
      bf16x8 av[8], bv[4];
      #pragma unroll
      for (int mi = 0; mi < 8; ++mi)
        av[mi] = *(const bf16x8*)&Asr[wr * 128 + mi * 16 + r][cc];
      #pragma unroll
      for (int ni = 0; ni < 4; ++ni)
        bv[ni] = *(const bf16x8*)&Bsr[wc * 64 + ni * 16 + r][cc];
      __builtin_amdgcn_s_setprio(1);
      #pragma unroll
      for (int ni = 0; ni < 4; ++ni)
        #pragma unroll
        for (int mi = 0; mi < 8; ++mi)
          acc[mi][ni] = __builtin_amdgcn_mfma_f32_16x16x32_bf16(
              av[mi], bv[ni], acc[mi][ni], 0, 0, 0);
      __builtin_amdgcn_s_setprio(0);
    }
    asm volatile("" ::: "memory");
    __builtin_amdgcn_s_barrier();                  // all reads of buf p done before re-stage
  }
  asm volatile("s_waitcnt vmcnt(0)" ::: "memory"); // drain wrap-stage before epilogue/endpgm

  // epilogue: C/D layout col=lane&15, row=quad*4+reg (verified convention)
  #pragma unroll
  for (int ni = 0; ni < 4; ++ni) {
    const int nn = n0 + wc * 64 + ni * 16 + r;
    const float bvv = bias[nn];
    #pragma unroll
    for (int mi = 0; mi < 8; ++mi) {
      #pragma unroll
      for (int v = 0; v < 4; ++v) {
        const int mm = m0 + wr * 128 + mi * 16 + quad * 4 + v;
        float val = acc[mi][ni][v] + bvv;
        if (MODE == EPI_GELU) {
          val = 0.5f * val * (1.0f + erff(val * 0.70710678118654752f));
          ((__bf16*)out)[(size_t)mm * N + nn] = (__bf16)val;
        } else if (MODE == EPI_QKV) {
          if (nn < 2048) {
            const float sv = (nn < 1024) ? val * 0.125f : val;  // fold 1/sqrt(HD) into Q
            ((__bf16*)out)[(size_t)mm * 2048 + nn] = (__bf16)sv;
          } else {
            const int c = nn - 2048, hh = c >> 6, dd = c & 63;
            const int bb = mm >> 11, tt = mm & 2047;
            vT[(size_t)((bb * 16 + hh) * 64 + dd) * 2048 + tt] = (__bf16)val;
          }
        }
      }
    }
  }
}

// ---------- GEMM64 (bf16 W): 128x64 tile, BK=64, EPI_RES; k-halves split ----------
__global__ __launch_bounds__(256, 2)
void gemm64_kernel(const __bf16* __restrict__ A, const __bf16* __restrict__ W,
                   const float* __restrict__ bias, float* __restrict__ out,
                   const float* __restrict__ res, int M, int N, int K)
{
  __shared__ __align__(16) __bf16 As0[128][32], As1[128][32];  // 16 KB
  __shared__ __align__(16) __bf16 Ws0[64][32],  Ws1[64][32];   //  8 KB
  const int tid = threadIdx.x;
  const int lane = tid & 63, w = tid >> 6;
  const int wr = w >> 1, wc = w & 1;
  const int quad = lane >> 4, r = lane & 15;
  const int m0 = blockIdx.x * 128, n0 = blockIdx.y * 64;

  floatx4 acc[4][2] = {};

  const __bf16* Ab = A + (size_t)m0 * K;
  const __bf16* Wb = W + (size_t)n0 * K;
  const int sr = tid >> 2, sc = (tid & 3) * 8;

  for (int k0 = 0; k0 < K; k0 += 64) {
    async16(Ab + (size_t)sr * K + k0 + sc,             &As0[sr][sc]);
    async16(Ab + (size_t)(sr + 64) * K + k0 + sc,      &As0[sr + 64][sc]);
    async16(Ab + (size_t)sr * K + k0 + 32 + sc,        &As1[sr][sc]);
    async16(Ab + (size_t)(sr + 64) * K + k0 + 32 + sc, &As1[sr + 64][sc]);
    async16(Wb + (size_t)sr * K + k0 + sc,             &Ws0[sr][sc]);
    async16(Wb + (size_t)sr * K + k0 + 32 + sc,        &Ws1[sr][sc]);
    __syncthreads();
    bf16x8 af0[4], af1[4];
    #pragma unroll
    for (int mi = 0; mi < 4; ++mi) {
      af0[mi] = *(const bf16x8*)&As0[wr * 64 + mi * 16 + r][quad * 8];
      af1[mi] = *(const bf16x8*)&As1[wr * 64 + mi * 16 + r][quad * 8];
    }
    #pragma unroll
    for (int ni = 0; ni < 2; ++ni) {
      const bf16x8 b0 = *(const bf16x8*)&Ws0[wc * 32 + ni * 16 + r][quad * 8];
      const bf16x8 b1 = *(const bf16x8*)&Ws1[wc * 32 + ni * 16 + r][quad * 8];
      #pragma unroll
      for (int mi = 0; mi < 4; ++mi) {
        acc[mi][ni] = __builtin_amdgcn_mfma_f32_16x16x32_bf16(af0[mi], b0, acc[mi][ni], 0, 0, 0);
        acc[mi][ni] = __builtin_amdgcn_mfma_f32_16x16x32_bf16(af1[mi], b1, acc[mi][ni], 0, 0, 0);
      }
    }
    __syncthreads();
  }

  #pragma unroll
  for (int ni = 0; ni < 2; ++ni) {
    const int nn = n0 + wc * 32 + ni * 16 + r;
    const float bv = bias[nn];
    #pragma unroll
    for (int mi = 0; mi < 4; ++mi) {
      #pragma unroll
      for (int v = 0; v < 4; ++v) {
        const int mm = m0 + wr * 64 + mi * 16 + quad * 4 + v;
        out[(size_t)mm * N + nn] = res[(size_t)mm * N + nn] + acc[mi][ni][v] + bv;
      }
    }
  }
}

// ---------- LEGACY GEMM (fp32 W) — fallback if workspace too small ----------
template<int MODE, int NT>
__global__ __launch_bounds__(256, 2)
void gemm_legacy_kernel(const __bf16* __restrict__ A, const float* __restrict__ W,
                        const float* __restrict__ bias, void* out,
                        const float* __restrict__ res, __bf16* __restrict__ vT,
                        int M, int N, int K)
{
  __shared__ __align__(16) __bf16 As[128][32];
  __shared__ __align__(16) __bf16 Ws[NT][32];
  const int tid = threadIdx.x;
  const int lane = tid & 63, w = tid >> 6;
  const int wr = w >> 1, wc = w & 1;
  const int quad = lane >> 4, r = lane & 15;
  constexpr int NACC = NT / 32;
  const int m0 = blockIdx.x * 128, n0 = blockIdx.y * NT;
  floatx4 acc[4][NACC] = {};
  const __bf16* Ab = A + (size_t)m0 * K;
  const float*  Wb = W + (size_t)n0 * K;
  const int arow = tid >> 2, ac = (tid & 3) * 8;
  const int wrow = tid >> 3, wc4 = (tid & 7) * 4;
  for (int k0 = 0; k0 < K; k0 += 32) {
    async16(Ab + (size_t)arow * K + k0 + ac, &As[arow][ac]);
    async16(Ab + (size_t)(arow + 64) * K + k0 + ac, &As[arow + 64][ac]);
    #pragma unroll
    for (int i = 0; i < NT / 32; ++i) {
      const int rw = wrow + 32 * i;
      const floatx4 f = *(const floatx4*)(Wb + (size_t)rw * K + k0 + wc4);
      bf16x4 h4 = { (__bf16)f[0], (__bf16)f[1], (__bf16)f[2], (__bf16)f[3] };
      *(bf16x4*)&Ws[rw][wc4] = h4;
    }
    __syncthreads();
    bf16x8 af[4];
    #pragma unroll
    for (int mi = 0; mi < 4; ++mi)
      af[mi] = *(const bf16x8*)&As[wr * 64 + mi * 16 + r][quad * 8];
    #pragma unroll
    for (int ni = 0; ni < NACC; ++ni) {
      bf16x8 bf = *(const bf16x8*)&Ws[wc * (NT / 2) + ni * 16 + r][quad * 8];
      #pragma unroll
      for (int mi = 0; mi < 4; ++mi)
        acc[mi][ni] = __builtin_amdgcn_mfma_f32_16x16x32_bf16(af[mi], bf, acc[mi][ni], 0, 0, 0);
    }
    __syncthreads();
  }
  #pragma unroll
  for (int ni = 0; ni < NACC; ++ni) {
    const int nn = n0 + wc * (NT / 2) + ni * 16 + r;
    const float bv = bias[nn];
    #pragma unroll
    for (int mi = 0; mi < 4; ++mi) {
      #pragma unroll
      for (int v = 0; v < 4; ++v) {
        const int mm = m0 + wr * 64 + mi * 16 + quad * 4 + v;
        float val = acc[mi][ni][v] + bv;
        if (MODE == EPI_GELU) {
          val = 0.5f * val * (1.0f + erff(val * 0.70710678118654752f));
          ((__bf16*)out)[(size_t)mm * N + nn] = (__bf16)val;
        } else if (MODE == EPI_RES) {
          ((float*)out)[(size_t)mm * N + nn] = res[(size_t)mm * N + nn] + val;
        } else if (MODE == EPI_QKV) {
          if (nn < 2048) {
            const float sv = (nn < 1024) ? val * 0.125f : val;
            ((__bf16*)out)[(size_t)mm * 2048 + nn] = (__bf16)sv;
          } else {
            const int c = nn - 2048, hh = c >> 6, dd = c & 63;
            const int bb = mm >> 11, t = mm & 2047;
            vT[(size_t)((bb * 16 + hh) * 64 + dd) * 2048 + t] = (__bf16)val;
          }
        }
      }
    }
  }
}

// ---------- Flash attention, transposed-MFMA formulation, 64-key tiles ----------
__global__ __launch_bounds__(256, 4)
void attn_kernel(const __bf16* __restrict__ qk,  // [B*T][2048]: cols 0..1023 Q(*0.125), 1024..2047 K
                 const __bf16* __restrict__ vT,  // [(b*16+h)*64+d][2048]
                 __bf16* __restrict__ out)       // [B*T][1024]
{
  __shared__ __align__(16) __bf16 Qs[2][64][32];
  __shared__ __align__(16) __bf16 Ks[2][64][32];
  __shared__ __align__(16) __bf16 Vs[2][64][32];
  __shared__ __align__(16) __bf16 Ps[4][2][16][32];
  const int tid = threadIdx.x, lane = tid & 63, w = tid >> 6;
  const int quad = lane >> 4, r = lane & 15;
  const int bh = blockIdx.x, b = bh >> 4, h = bh & 15;
  const int yk = blockIdx.y >> 3, yj = blockIdx.y & 7;
  const int qt = (yk << 3) | ((yk & 1) ? (7 - yj) : yj);
  const int q0 = qt * 64;

  {
    const __bf16* qb = qk + ((size_t)(b * SEQ + q0)) * 2048 + h * 64;
    #pragma unroll
    for (int rd = 0; rd < 2; ++rd) {
      const int c = rd * 256 + tid, half = c >> 8, row = (c >> 2) & 63, c8 = (c & 3) * 8;
      async16(qb + (size_t)row * 2048 + half * 32 + c8, &Qs[half][row][c8]);
    }
  }
  __syncthreads();
  const bf16x8 qf0 = *(const bf16x8*)&Qs[0][w * 16 + r][quad * 8];
  const bf16x8 qf1 = *(const bf16x8*)&Qs[1][w * 16 + r][quad * 8];

  const int q = q0 + w * 16 + r;
  float m_i = -INFINITY, l_i = 0.0f;
  floatx4 ot[4] = {};
  const float slope = exp2f(-0.5f * (float)(h + 1));
  const float sq = slope * (float)q;

  const __bf16* kb0 = qk + ((size_t)(b * SEQ)) * 2048 + 1024 + h * 64;
  const __bf16* vb0 = vT + ((size_t)(bh * 64)) * 2048;

  for (int kt = 0; kt <= qt; ++kt) {
    const int kbase = kt << 6;
    #pragma unroll
    for (int rd = 0; rd < 2; ++rd) {
      const int c = rd * 256 + tid, half = c >> 8, row = (c >> 2) & 63, c8 = (c & 3) * 8;
      async16(kb0 + (size_t)(kbase + row) * 2048 + half * 32 + c8, &Ks[half][row][c8]);
    }
    #pragma unroll
    for (int rd = 0; rd < 2; ++rd) {
      const int c = rd * 256 + tid, kb = c >> 8, d = (c >> 2) & 63, c8 = (c & 3) * 8;
      async16(vb0 + (size_t)d * 2048 + kbase + kb * 32 + c8, &Vs[kb][d][c8]);
    }
    __syncthreads();

    floatx4 st[4];
    #pragma unroll
    for (int t = 0; t < 4; ++t) {
      floatx4 z = { 0.0f, 0.0f, 0.0f, 0.0f };
      const bf16x8 kf0 = *(const bf16x8*)&Ks[0][t * 16 + r][quad * 8];
      const bf16x8 kf1 = *(const bf16x8*)&Ks[1][t * 16 + r][quad * 8];
      z = __builtin_amdgcn_mfma_f32_16x16x32_bf16(kf0, qf0, z, 0, 0, 0);
      st[t] = __builtin_amdgcn_mfma_f32_16x16x32_bf16(kf1, qf1, z, 0, 0, 0);
    }
    float mloc = -INFINITY;
    if (kt == qt) {
      #pragma unroll
      for (int t = 0; t < 4; ++t)
        #pragma unroll
        for (int v = 0; v < 4; ++v) {
          const int key = kbase + t * 16 + quad * 4 + v;
          float sv = st[t][v] + slope * (float)key - sq;
          sv = (key <= q) ? sv : -INFINITY;
          st[t][v] = sv;
          mloc = fmaxf(mloc, sv);
        }
    } else {
      #pragma unroll
      for (int t = 0; t < 4; ++t)
        #pragma unroll
        for (int v = 0; v < 4; ++v) {
          const int key = kbase + t * 16 + quad * 4 + v;
          const float sv = st[t][v] + slope * (float)key - sq;
          st[t][v] = sv;
          mloc = fmaxf(mloc, sv);
        }
    }
    mloc = fmaxf(mloc, __shfl_xor(mloc, 16));
    mloc = fmaxf(mloc, __shfl_xor(mloc, 32));
    const float mn = fmaxf(m_i, mloc);
    const float alpha = __expf(m_i - mn);
    m_i = mn;
    float rsum = 0.0f;
    #pragma unroll
    for (int t = 0; t < 4; ++t) {
      bf16x4 p4;
      #pragma unroll
      for (int v = 0; v < 4; ++v) {
        const float p = __expf(st[t][v] - mn);
        rsum += p;
        p4[v] = (__bf16)p;
      }
      *(bf16x4*)&Ps[w][t >> 1][r][(t & 1) * 16 + quad * 4] = p4;
    }
    rsum += __shfl_xor(rsum, 16);
    rsum += __shfl_xor(rsum, 32);
    l_i = l_i * alpha + rsum;
    #pragma unroll
    for (int dt = 0; dt < 4; ++dt) ot[dt] *= alpha;

    #pragma unroll
    for (int kb = 0; kb < 2; ++kb) {
      const bf16x8 pf = *(const bf16x8*)&Ps[w][kb][r][quad * 8];
      #pragma unroll
      for (int dt = 0; dt < 4; ++dt) {
        const bf16x8 vf = *(const bf16x8*)&Vs[kb][dt * 16 + r][quad * 8];
        ot[dt] = __builtin_amdgcn_mfma_f32_16x16x32_bf16(vf, pf, ot[dt], 0, 0, 0);
      }
    }
    __syncthreads();
  }

  const float linv = 1.0f / l_i;
  __bf16* ob = out + (size_t)(b * SEQ + q) * D_MODEL + h * 64;
  #pragma unroll
  for (int dt = 0; dt < 4; ++dt) {
    bf16x4 o4 = { (__bf16)(ot[dt][0] * linv), (__bf16)(ot[dt][1] * linv),
                  (__bf16)(ot[dt][2] * linv), (__bf16)(ot[dt][3] * linv) };
    *(bf16x4*)(ob + dt * 16 + quad * 4) = o4;
  }
}

// ---------- driver ----------
extern "C" void kernel_launch(void* const* d_in, const int* in_sizes, int n_in,
                              void* d_out, int out_size, void* d_ws, size_t ws_size,
                              hipStream_t stream)
{
  (void)in_sizes; (void)n_in; (void)out_size;
  const float* x    = (const float*)d_in[0];
  const float* inW  = (const float*)d_in[1];
  const float* inB  = (const float*)d_in[2];
  const float* outW = (const float*)d_in[3];
  const float* outB = (const float*)d_in[4];
  const float* f1W  = (const float*)d_in[5];
  const float* f1B  = (const float*)d_in[6];
  const float* f2W  = (const float*)d_in[7];
  const float* f2B  = (const float*)d_in[8];
  const float* ln1W = (const float*)d_in[9];
  const float* ln1B = (const float*)d_in[10];
  const float* ln2W = (const float*)d_in[11];
  const float* ln2B = (const float*)d_in[12];
  const float* fnW  = (const float*)d_in[13];
  const float* fnB  = (const float*)d_in[14];

  char* ws = (char*)d_ws;
  float*  x_cur = (float*)(ws);                    // 16.78 MB fp32 residual
  __bf16* xn    = (__bf16*)(ws + 16777216);        //  8.39 MB
  __bf16* qk    = (__bf16*)(ws + 25165824);        // 16.78 MB
  __bf16* vT    = (__bf16*)(ws + 41943040);        //  8.39 MB
  __bf16* attn  = (__bf16*)(ws + 50331648);        //  8.39 MB
  __bf16* hbuf  = (__bf16*)(ws + 25165824);        // 33.55 MB, aliases qk/vT/attn (dead by FFN1)
  // bf16 weight cache (one-time convert per launch)
  __bf16* inWb  = (__bf16*)(ws + 58720256);        // 25.17 MB
  __bf16* outWb = (__bf16*)(ws + 83886080);        //  8.39 MB
  __bf16* f1Wb  = (__bf16*)(ws + 92274688);        // 33.55 MB
  __bf16* f2Wb  = (__bf16*)(ws + 125829120);       // 33.55 MB -> need 159,383,552 B
  const bool bf16w = ws_size >= (size_t)159383552;

  hipMemcpyAsync(x_cur, x, (size_t)16777216, hipMemcpyDeviceToDevice, stream);

  if (bf16w) {
    cvtw_kernel<<<dim3(12288), dim3(256), 0, stream>>>(inW,  inWb);
    cvtw_kernel<<<dim3(4096),  dim3(256), 0, stream>>>(outW, outWb);
    cvtw_kernel<<<dim3(16384), dim3(256), 0, stream>>>(f1W,  f1Wb);
    cvtw_kernel<<<dim3(16384), dim3(256), 0, stream>>>(f2W,  f2Wb);
  }

  for (int i = 0; i < 4; ++i) {
    ln_kernel<true><<<dim3(4096), dim3(256), 0, stream>>>(
        x_cur, ln1W + i * 1024, ln1B + i * 1024, xn);
    if (bf16w)
      gemm256_kernel<EPI_QKV><<<dim3(16, 12), dim3(512), 0, stream>>>(
          xn, inWb + (size_t)i * 3072 * 1024, inB + (size_t)i * 3072,
          qk, vT, 4096, 3072, 1024);
    else
      gemm_legacy_kernel<EPI_QKV, 128><<<dim3(32, 24), dim3(256), 0, stream>>>(
          xn, inW + (size_t)i * 3072 * 1024, inB + (size_t)i * 3072,
          qk, nullptr, vT, 4096, 3072, 1024);
    attn_kernel<<<dim3(32, 32), dim3(256), 0, stream>>>(qk, vT, attn);
    if (bf16w)
      gemm64_kernel<<<dim3(32, 16), dim3(256), 0, stream>>>(
          attn, outWb + (size_t)i * 1024 * 1024, outB + (size_t)i * 1024,
          x_cur, x_cur, 4096, 1024, 1024);
    else
      gemm_legacy_kernel<EPI_RES, 64><<<dim3(32, 16), dim3(256), 0, stream>>>(
          attn, outW + (size_t)i * 1024 * 1024, outB + (size_t)i * 1024,
          x_cur, x_cur, nullptr, 4096, 1024, 1024);
    ln_kernel<true><<<dim3(4096), dim3(256), 0, stream>>>(
        x_cur, ln2W + i * 1024, ln2B + i * 1024, xn);
    if (bf16w)
      gemm256_kernel<EPI_GELU><<<dim3(16, 16), dim3(512), 0, stream>>>(
          xn, f1Wb + (size_t)i * 4096 * 1024, f1B + (size_t)i * 4096,
          hbuf, nullptr, 4096, 4096, 1024);
    else
      gemm_legacy_kernel<EPI_GELU, 128><<<dim3(32, 32), dim3(256), 0, stream>>>(
          xn, f1W + (size_t)i * 4096 * 1024, f1B + (size_t)i * 4096,
          hbuf, nullptr, nullptr, 4096, 4096, 1024);
    if (bf16w)
      gemm64_kernel<<<dim3(32, 16), dim3(256), 0, stream>>>(
          hbuf, f2Wb + (size_t)i * 1024 * 4096, f2B + (size_t)i * 1024,
          x_cur, x_cur, 4096, 1024, 4096);
    else
      gemm_legacy_kernel<EPI_RES, 64><<<dim3(32, 16), dim3(256), 0, stream>>>(
          hbuf, f2W + (size_t)i * 1024 * 4096, f2B + (size_t)i * 1024,
          x_cur, x_cur, nullptr, 4096, 1024, 4096);
  }
  ln_kernel<false><<<dim3(4096), dim3(256), 0, stream>>>(x_cur, fnW, fnB, d_out);
}

// Round 4
// 1268.624 us; speedup vs baseline: 1.1780x; 1.0638x over previous
//
#include <hip/hip_runtime.h>
#include <hip/hip_bf16.h>
#include <math.h>

// ---------- types ----------
typedef __bf16 bf16x8 __attribute__((ext_vector_type(8)));
typedef __bf16 bf16x4 __attribute__((ext_vector_type(4)));
typedef float  floatx4 __attribute__((ext_vector_type(4)));

#define D_MODEL 1024
#define SEQ     2048
#define NHEAD   16
#define HD      64

__device__ __forceinline__ void async16(const void* g, void* l) {
  __builtin_amdgcn_global_load_lds((const __attribute__((address_space(1))) void*)g,
                                   (__attribute__((address_space(3))) void*)l, 16, 0, 0);
}

// ---------- weight fp32 -> bf16 convert ----------
__global__ __launch_bounds__(256)
void cvtw_kernel(const float* __restrict__ in, __bf16* __restrict__ out) {
  const size_t i = ((size_t)blockIdx.x * 256 + threadIdx.x) * 4;
  const floatx4 f = *(const floatx4*)(in + i);
  bf16x4 o = { (__bf16)f[0], (__bf16)f[1], (__bf16)f[2], (__bf16)f[3] };
  *(bf16x4*)(out + i) = o;
}

// ---------- LayerNorm: fp32 row(1024) -> bf16 (or fp32 for final) ----------
template<bool OUT_BF16>
__global__ __launch_bounds__(256)
void ln_kernel(const float* __restrict__ x, const float* __restrict__ w,
               const float* __restrict__ b, void* __restrict__ out)
{
  const int row = blockIdx.x;
  const int tid = threadIdx.x;
  const floatx4 f = *(const floatx4*)(x + (size_t)row * D_MODEL + tid * 4);
  float s = f[0] + f[1] + f[2] + f[3];
  #pragma unroll
  for (int off = 1; off < 64; off <<= 1) s += __shfl_xor(s, off);
  __shared__ float red[8];
  const int wv = tid >> 6;
  if ((tid & 63) == 0) red[wv] = s;
  __syncthreads();
  const float mu = (red[0] + red[1] + red[2] + red[3]) * (1.0f / 1024.0f);
  float d0 = f[0] - mu, d1 = f[1] - mu, d2 = f[2] - mu, d3 = f[3] - mu;
  float ss = d0 * d0 + d1 * d1 + d2 * d2 + d3 * d3;
  #pragma unroll
  for (int off = 1; off < 64; off <<= 1) ss += __shfl_xor(ss, off);
  if ((tid & 63) == 0) red[4 + wv] = ss;
  __syncthreads();
  const float rstd = rsqrtf((red[4] + red[5] + red[6] + red[7]) * (1.0f / 1024.0f) + 1e-5f);
  const floatx4 wv4 = *(const floatx4*)(w + tid * 4);
  const floatx4 bv4 = *(const floatx4*)(b + tid * 4);
  const float y0 = d0 * rstd * wv4[0] + bv4[0];
  const float y1 = d1 * rstd * wv4[1] + bv4[1];
  const float y2 = d2 * rstd * wv4[2] + bv4[2];
  const float y3 = d3 * rstd * wv4[3] + bv4[3];
  if (OUT_BF16) {
    bf16x4 o = { (__bf16)y0, (__bf16)y1, (__bf16)y2, (__bf16)y3 };
    *(bf16x4*)((__bf16*)out + (size_t)row * D_MODEL + tid * 4) = o;
  } else {
    floatx4 o = { y0, y1, y2, y3 };
    *(floatx4*)((float*)out + (size_t)row * D_MODEL + tid * 4) = o;
  }
}

#define EPI_GELU 1
#define EPI_RES  2
#define EPI_QKV  3

// ---------- GEMM256: 256x256 tile, BK=64, 8 waves, 4 fine phases per K-tile ----------
// T2 swizzle (pre-swizzled global source, XOR on read; 0 conflicts measured).
// T3/T4: stages issued at P0/P1, certified by P3's __syncthreads (distance >= 2.5
// phases ~ 1400cyc > HBM latency; no zero-distance drain).  T5 setprio per cluster.
// 24 ds_read_b128 / wave / K-tile (minimal): B-lo fragments register-cached P0->P3.
// Epilogue: C staged in LDS (dead after K-loop), drained with bf16x8 stores.
template<int MODE>
__global__ __launch_bounds__(512, 2)
void gemm256_kernel(const __bf16* __restrict__ A, const __bf16* __restrict__ W,
                    const float* __restrict__ bias, void* out,
                    __bf16* __restrict__ vT, int M, int N, int K)
{
  __shared__ __align__(16) char smem[131072];
  __bf16 (*As)[256][64] = reinterpret_cast<__bf16 (*)[256][64]>(smem);
  __bf16 (*Bs)[256][64] = reinterpret_cast<__bf16 (*)[256][64]>(smem + 65536);

  const int tid = threadIdx.x;
  const int lane = tid & 63, wv = tid >> 6;
  const int wr = wv >> 2, wc = wv & 3;              // 2 x 4 wave grid
  const int quad = lane >> 4, r = lane & 15;
  const int sw = r & 7;
  const int m0 = blockIdx.x * 256, n0 = blockIdx.y * 256;
  const __bf16* Ab = A + (size_t)m0 * K;
  const __bf16* Wb = W + (size_t)n0 * K;

  floatx4 acc[8][4] = {};                           // 128x64 per wave

  const int nt = K >> 6;

  // prologue: stage tile 0 -> buf 0, drain, barrier
  #pragma unroll
  for (int j = 0; j < 4; ++j) {
    const int ch = j * 512 + tid;
    const int row = ch >> 3, c16 = ch & 7;
    const int gcb = (c16 ^ (row & 7)) * 8;
    async16(Ab + (size_t)row * K + gcb, &As[0][row][c16 * 8]);
  }
  #pragma unroll
  for (int j = 0; j < 4; ++j) {
    const int ch = j * 512 + tid;
    const int row = ch >> 3, c16 = ch & 7;
    const int gcb = (c16 ^ (row & 7)) * 8;
    async16(Wb + (size_t)row * K + gcb, &Bs[0][row][c16 * 8]);
  }
  __syncthreads();

  for (int t = 0; t < nt; ++t) {
    const int pr = t & 1;
    const __bf16 (*Asr)[64] = As[pr];
    const __bf16 (*Bsr)[64] = Bs[pr];
    const bool pf = (t + 1 < nt);
    const int kn = (t + 1) << 6;

    bf16x8 a0[2][4], b0[2][2], b1[2][2];

    // ---- P0: stage A(t+1); read A(lo half) + B(lo); MFMA quad (0,0)
    if (pf) {
      #pragma unroll
      for (int j = 0; j < 4; ++j) {
        const int ch = j * 512 + tid;
        const int row = ch >> 3, c16 = ch & 7;
        const int gcb = (c16 ^ (row & 7)) * 8;
        async16(Ab + (size_t)row * K + kn + gcb, &As[pr ^ 1][row][c16 * 8]);
      }
    }
    #pragma unroll
    for (int kk = 0; kk < 2; ++kk) {
      const int cc = ((kk * 4 + quad) ^ sw) * 8;
      #pragma unroll
      for (int mi = 0; mi < 4; ++mi)
        a0[kk][mi] = *(const bf16x8*)&Asr[wr * 128 + mi * 16 + r][cc];
      #pragma unroll
      for (int ni = 0; ni < 2; ++ni)
        b0[kk][ni] = *(const bf16x8*)&Bsr[wc * 64 + ni * 16 + r][cc];
    }
    __builtin_amdgcn_s_setprio(1);
    #pragma unroll
    for (int kk = 0; kk < 2; ++kk)
      #pragma unroll
      for (int ni = 0; ni < 2; ++ni)
        #pragma unroll
        for (int mi = 0; mi < 4; ++mi)
          acc[mi][ni] = __builtin_amdgcn_mfma_f32_16x16x32_bf16(
              a0[kk][mi], b0[kk][ni], acc[mi][ni], 0, 0, 0);
    __builtin_amdgcn_s_setprio(0);
    asm volatile("" ::: "memory");
    __builtin_amdgcn_s_barrier();
    asm volatile("" ::: "memory");

    // ---- P1: stage B(t+1); read B(hi); MFMA quad (0,1)
    if (pf) {
      #pragma unroll
      for (int j = 0; j < 4; ++j) {
        const int ch = j * 512 + tid;
        const int row = ch >> 3, c16 = ch & 7;
        const int gcb = (c16 ^ (row & 7)) * 8;
        async16(Wb + (size_t)row * K + kn + gcb, &Bs[pr ^ 1][row][c16 * 8]);
      }
    }
    #pragma unroll
    for (int kk = 0; kk < 2; ++kk) {
      const int cc = ((kk * 4 + quad) ^ sw) * 8;
      #pragma unroll
      for (int ni = 0; ni < 2; ++ni)
        b1[kk][ni] = *(const bf16x8*)&Bsr[wc * 64 + 32 + ni * 16 + r][cc];
    }
    __builtin_amdgcn_s_setprio(1);
    #pragma unroll
    for (int kk = 0; kk < 2; ++kk)
      #pragma unroll
      for (int ni = 0; ni < 2; ++ni)
        #pragma unroll
        for (int mi = 0; mi < 4; ++mi)
          acc[mi][2 + ni] = __builtin_amdgcn_mfma_f32_16x16x32_bf16(
              a0[kk][mi], b1[kk][ni], acc[mi][2 + ni], 0, 0, 0);
    __builtin_amdgcn_s_setprio(0);
    asm volatile("" ::: "memory");
    __builtin_amdgcn_s_barrier();
    asm volatile("" ::: "memory");

    // ---- P2: read A(hi half); MFMA quad (1,1) (b1 still hot)
    #pragma unroll
    for (int kk = 0; kk < 2; ++kk) {
      const int cc = ((kk * 4 + quad) ^ sw) * 8;
      #pragma unroll
      for (int mi = 0; mi < 4; ++mi)
        a0[kk][mi] = *(const bf16x8*)&Asr[wr * 128 + 64 + mi * 16 + r][cc];
    }
    __builtin_amdgcn_s_setprio(1);
    #pragma unroll
    for (int kk = 0; kk < 2; ++kk)
      #pragma unroll
      for (int ni = 0; ni < 2; ++ni)
        #pragma unroll
        for (int mi = 0; mi < 4; ++mi)
          acc[4 + mi][2 + ni] = __builtin_amdgcn_mfma_f32_16x16x32_bf16(
              a0[kk][mi], b1[kk][ni], acc[4 + mi][2 + ni], 0, 0, 0);
    __builtin_amdgcn_s_setprio(0);
    asm volatile("" ::: "memory");
    __builtin_amdgcn_s_barrier();
    asm volatile("" ::: "memory");

    // ---- P3: MFMA quad (1,0) reusing b0 regs; certify tile t+1 (vmcnt+lgkm+barrier)
    __builtin_amdgcn_s_setprio(1);
    #pragma unroll
    for (int kk = 0; kk < 2; ++kk)
      #pragma unroll
      for (int ni = 0; ni < 2; ++ni)
        #pragma unroll
        for (int mi = 0; mi < 4; ++mi)
          acc[4 + mi][ni] = __builtin_amdgcn_mfma_f32_16x16x32_bf16(
              a0[kk][mi], b0[kk][ni], acc[4 + mi][ni], 0, 0, 0);
    __builtin_amdgcn_s_setprio(0);
    __syncthreads();   // drains vmcnt/lgkm: stage issued >=2.5 phases ago -> no stall
  }

  // ---------- epilogue through LDS (smem dead after K-loop) ----------
  __bf16 (*Cs)[264] = reinterpret_cast<__bf16 (*)[264]>(smem);   // [128][264] row-major
  __bf16 (*Ct)[136] = reinterpret_cast<__bf16 (*)[136]>(smem);   // [256][136] transposed
  const bool vblock = (MODE == EPI_QKV) && (n0 >= 2048);
  const size_t ostride = (MODE == EPI_QKV) ? (size_t)2048 : (size_t)N;

  #pragma unroll
  for (int pass = 0; pass < 2; ++pass) {
    if (wr == pass) {
      #pragma unroll
      for (int ni = 0; ni < 4; ++ni) {
        const int nn_l = wc * 64 + ni * 16 + r;
        const float bvv = bias[n0 + nn_l];
        #pragma unroll
        for (int mi = 0; mi < 8; ++mi) {
          if (vblock) {
            bf16x4 o4;
            #pragma unroll
            for (int v = 0; v < 4; ++v) o4[v] = (__bf16)(acc[mi][ni][v] + bvv);
            *(bf16x4*)&Ct[nn_l][mi * 16 + quad * 4] = o4;
          } else {
            #pragma unroll
            for (int v = 0; v < 4; ++v) {
              float val = acc[mi][ni][v] + bvv;
              if (MODE == EPI_GELU)
                val = 0.5f * val * (1.0f + erff(val * 0.70710678118654752f));
              if (MODE == EPI_QKV && (n0 + nn_l) < 1024) val *= 0.125f;
              Cs[mi * 16 + quad * 4 + v][nn_l] = (__bf16)val;
            }
          }
        }
      }
    }
    __syncthreads();
    if (vblock) {
      const int c0 = n0 - 2048;
      const int bb = m0 >> 11;
      #pragma unroll
      for (int rd = 0; rd < 8; ++rd) {
        const int idx = rd * 512 + tid;
        const int rn = idx >> 4, ch = idx & 15;
        const bf16x8 o = *(const bf16x8*)&Ct[rn][ch * 8];
        const int c = c0 + rn, hh = c >> 6, dd = c & 63;
        const int tt = (m0 & 2047) + pass * 128 + ch * 8;
        *(bf16x8*)(vT + ((size_t)((bb * 16 + hh) * 64 + dd)) * 2048 + tt) = o;
      }
    } else {
      #pragma unroll
      for (int rd = 0; rd < 8; ++rd) {
        const int idx = rd * 512 + tid;
        const int rowm = idx >> 5, ch = idx & 31;
        const bf16x8 o = *(const bf16x8*)&Cs[rowm][ch * 8];
        const int mm = m0 + pass * 128 + rowm;
        const int nn = n0 + ch * 8;
        *(bf16x8*)((__bf16*)out + (size_t)mm * ostride + nn) = o;
      }
    }
    __syncthreads();
  }
}

// ---------- GEMM64 (bf16 W): 128x64 tile, BK=64, EPI_RES; k-halves split ----------
__global__ __launch_bounds__(256, 2)
void gemm64_kernel(const __bf16* __restrict__ A, const __bf16* __restrict__ W,
                   const float* __restrict__ bias, float* __restrict__ out,
                   const float* __restrict__ res, int M, int N, int K)
{
  __shared__ __align__(16) __bf16 As0[128][32], As1[128][32];  // 16 KB
  __shared__ __align__(16) __bf16 Ws0[64][32],  Ws1[64][32];   //  8 KB
  const int tid = threadIdx.x;
  const int lane = tid & 63, w = tid >> 6;
  const int wr = w >> 1, wc = w & 1;
  const int quad = lane >> 4, r = lane & 15;
  const int m0 = blockIdx.x * 128, n0 = blockIdx.y * 64;

  floatx4 acc[4][2] = {};

  const __bf16* Ab = A + (size_t)m0 * K;
  const __bf16* Wb = W + (size_t)n0 * K;
  const int sr = tid >> 2, sc = (tid & 3) * 8;

  for (int k0 = 0; k0 < K; k0 += 64) {
    async16(Ab + (size_t)sr * K + k0 + sc,             &As0[sr][sc]);
    async16(Ab + (size_t)(sr + 64) * K + k0 + sc,      &As0[sr + 64][sc]);
    async16(Ab + (size_t)sr * K + k0 + 32 + sc,        &As1[sr][sc]);
    async16(Ab + (size_t)(sr + 64) * K + k0 + 32 + sc, &As1[sr + 64][sc]);
    async16(Wb + (size_t)sr * K + k0 + sc,             &Ws0[sr][sc]);
    async16(Wb + (size_t)sr * K + k0 + 32 + sc,        &Ws1[sr][sc]);
    __syncthreads();
    bf16x8 af0[4], af1[4];
    #pragma unroll
    for (int mi = 0; mi < 4; ++mi) {
      af0[mi] = *(const bf16x8*)&As0[wr * 64 + mi * 16 + r][quad * 8];
      af1[mi] = *(const bf16x8*)&As1[wr * 64 + mi * 16 + r][quad * 8];
    }
    #pragma unroll
    for (int ni = 0; ni < 2; ++ni) {
      const bf16x8 b0 = *(const bf16x8*)&Ws0[wc * 32 + ni * 16 + r][quad * 8];
      const bf16x8 b1 = *(const bf16x8*)&Ws1[wc * 32 + ni * 16 + r][quad * 8];
      #pragma unroll
      for (int mi = 0; mi < 4; ++mi) {
        acc[mi][ni] = __builtin_amdgcn_mfma_f32_16x16x32_bf16(af0[mi], b0, acc[mi][ni], 0, 0, 0);
        acc[mi][ni] = __builtin_amdgcn_mfma_f32_16x16x32_bf16(af1[mi], b1, acc[mi][ni], 0, 0, 0);
      }
    }
    __syncthreads();
  }

  #pragma unroll
  for (int ni = 0; ni < 2; ++ni) {
    const int nn = n0 + wc * 32 + ni * 16 + r;
    const float bv = bias[nn];
    #pragma unroll
    for (int mi = 0; mi < 4; ++mi) {
      #pragma unroll
      for (int v = 0; v < 4; ++v) {
        const int mm = m0 + wr * 64 + mi * 16 + quad * 4 + v;
        out[(size_t)mm * N + nn] = res[(size_t)mm * N + nn] + acc[mi][ni][v] + bv;
      }
    }
  }
}

// ---------- LEGACY GEMM (fp32 W) — fallback if workspace too small ----------
template<int MODE, int NT>
__global__ __launch_bounds__(256, 2)
void gemm_legacy_kernel(const __bf16* __restrict__ A, const float* __restrict__ W,
                        const float* __restrict__ bias, void* out,
                        const float* __restrict__ res, __bf16* __restrict__ vT,
                        int M, int N, int K)
{
  __shared__ __align__(16) __bf16 As[128][32];
  __shared__ __align__(16) __bf16 Ws[NT][32];
  const int tid = threadIdx.x;
  const int lane = tid & 63, w = tid >> 6;
  const int wr = w >> 1, wc = w & 1;
  const int quad = lane >> 4, r = lane & 15;
  constexpr int NACC = NT / 32;
  const int m0 = blockIdx.x * 128, n0 = blockIdx.y * NT;
  floatx4 acc[4][NACC] = {};
  const __bf16* Ab = A + (size_t)m0 * K;
  const float*  Wb = W + (size_t)n0 * K;
  const int arow = tid >> 2, ac = (tid & 3) * 8;
  const int wrow = tid >> 3, wc4 = (tid & 7) * 4;
  for (int k0 = 0; k0 < K; k0 += 32) {
    async16(Ab + (size_t)arow * K + k0 + ac, &As[arow][ac]);
    async16(Ab + (size_t)(arow + 64) * K + k0 + ac, &As[arow + 64][ac]);
    #pragma unroll
    for (int i = 0; i < NT / 32; ++i) {
      const int rw = wrow + 32 * i;
      const floatx4 f = *(const floatx4*)(Wb + (size_t)rw * K + k0 + wc4);
      bf16x4 h4 = { (__bf16)f[0], (__bf16)f[1], (__bf16)f[2], (__bf16)f[3] };
      *(bf16x4*)&Ws[rw][wc4] = h4;
    }
    __syncthreads();
    bf16x8 af[4];
    #pragma unroll
    for (int mi = 0; mi < 4; ++mi)
      af[mi] = *(const bf16x8*)&As[wr * 64 + mi * 16 + r][quad * 8];
    #pragma unroll
    for (int ni = 0; ni < NACC; ++ni) {
      bf16x8 bf = *(const bf16x8*)&Ws[wc * (NT / 2) + ni * 16 + r][quad * 8];
      #pragma unroll
      for (int mi = 0; mi < 4; ++mi)
        acc[mi][ni] = __builtin_amdgcn_mfma_f32_16x16x32_bf16(af[mi], bf, acc[mi][ni], 0, 0, 0);
    }
    __syncthreads();
  }
  #pragma unroll
  for (int ni = 0; ni < NACC; ++ni) {
    const int nn = n0 + wc * (NT / 2) + ni * 16 + r;
    const float bv = bias[nn];
    #pragma unroll
    for (int mi = 0; mi < 4; ++mi) {
      #pragma unroll
      for (int v = 0; v < 4; ++v) {
        const int mm = m0 + wr * 64 + mi * 16 + quad * 4 + v;
        float val = acc[mi][ni][v] + bv;
        if (MODE == EPI_GELU) {
          val = 0.5f * val * (1.0f + erff(val * 0.70710678118654752f));
          ((__bf16*)out)[(size_t)mm * N + nn] = (__bf16)val;
        } else if (MODE == EPI_RES) {
          ((float*)out)[(size_t)mm * N + nn] = res[(size_t)mm * N + nn] + val;
        } else if (MODE == EPI_QKV) {
          if (nn < 2048) {
            const float sv = (nn < 1024) ? val * 0.125f : val;
            ((__bf16*)out)[(size_t)mm * 2048 + nn] = (__bf16)sv;
          } else {
            const int c = nn - 2048, hh = c >> 6, dd = c & 63;
            const int bb = mm >> 11, t = mm & 2047;
            vT[(size_t)((bb * 16 + hh) * 64 + dd) * 2048 + t] = (__bf16)val;
          }
        }
      }
    }
  }
}

// ---------- Flash attention, transposed-MFMA formulation, 64-key tiles ----------
__global__ __launch_bounds__(256, 4)
void attn_kernel(const __bf16* __restrict__ qk,  // [B*T][2048]: cols 0..1023 Q(*0.125), 1024..2047 K
                 const __bf16* __restrict__ vT,  // [(b*16+h)*64+d][2048]
                 __bf16* __restrict__ out)       // [B*T][1024]
{
  __shared__ __align__(16) __bf16 Qs[2][64][32];
  __shared__ __align__(16) __bf16 Ks[2][64][32];
  __shared__ __align__(16) __bf16 Vs[2][64][32];
  __shared__ __align__(16) __bf16 Ps[4][2][16][32];
  const int tid = threadIdx.x, lane = tid & 63, w = tid >> 6;
  const int quad = lane >> 4, r = lane & 15;
  const int bh = blockIdx.x, b = bh >> 4, h = bh & 15;
  const int yk = blockIdx.y >> 3, yj = blockIdx.y & 7;
  const int qt = (yk << 3) | ((yk & 1) ? (7 - yj) : yj);
  const int q0 = qt * 64;

  {
    const __bf16* qb = qk + ((size_t)(b * SEQ + q0)) * 2048 + h * 64;
    #pragma unroll
    for (int rd = 0; rd < 2; ++rd) {
      const int c = rd * 256 + tid, half = c >> 8, row = (c >> 2) & 63, c8 = (c & 3) * 8;
      async16(qb + (size_t)row * 2048 + half * 32 + c8, &Qs[half][row][c8]);
    }
  }
  __syncthreads();
  const bf16x8 qf0 = *(const bf16x8*)&Qs[0][w * 16 + r][quad * 8];
  const bf16x8 qf1 = *(const bf16x8*)&Qs[1][w * 16 + r][quad * 8];

  const int q = q0 + w * 16 + r;
  float m_i = -INFINITY, l_i = 0.0f;
  floatx4 ot[4] = {};
  const float slope = exp2f(-0.5f * (float)(h + 1));
  const float sq = slope * (float)q;

  const __bf16* kb0 = qk + ((size_t)(b * SEQ)) * 2048 + 1024 + h * 64;
  const __bf16* vb0 = vT + ((size_t)(bh * 64)) * 2048;

  for (int kt = 0; kt <= qt; ++kt) {
    const int kbase = kt << 6;
    #pragma unroll
    for (int rd = 0; rd < 2; ++rd) {
      const int c = rd * 256 + tid, half = c >> 8, row = (c >> 2) & 63, c8 = (c & 3) * 8;
      async16(kb0 + (size_t)(kbase + row) * 2048 + half * 32 + c8, &Ks[half][row][c8]);
    }
    #pragma unroll
    for (int rd = 0; rd < 2; ++rd) {
      const int c = rd * 256 + tid, kb = c >> 8, d = (c >> 2) & 63, c8 = (c & 3) * 8;
      async16(vb0 + (size_t)d * 2048 + kbase + kb * 32 + c8, &Vs[kb][d][c8]);
    }
    __syncthreads();

    floatx4 st[4];
    #pragma unroll
    for (int t = 0; t < 4; ++t) {
      floatx4 z = { 0.0f, 0.0f, 0.0f, 0.0f };
      const bf16x8 kf0 = *(const bf16x8*)&Ks[0][t * 16 + r][quad * 8];
      const bf16x8 kf1 = *(const bf16x8*)&Ks[1][t * 16 + r][quad * 8];
      z = __builtin_amdgcn_mfma_f32_16x16x32_bf16(kf0, qf0, z, 0, 0, 0);
      st[t] = __builtin_amdgcn_mfma_f32_16x16x32_bf16(kf1, qf1, z, 0, 0, 0);
    }
    float mloc = -INFINITY;
    if (kt == qt) {
      #pragma unroll
      for (int t = 0; t < 4; ++t)
        #pragma unroll
        for (int v = 0; v < 4; ++v) {
          const int key = kbase + t * 16 + quad * 4 + v;
          float sv = st[t][v] + slope * (float)key - sq;
          sv = (key <= q) ? sv : -INFINITY;
          st[t][v] = sv;
          mloc = fmaxf(mloc, sv);
        }
    } else {
      #pragma unroll
      for (int t = 0; t < 4; ++t)
        #pragma unroll
        for (int v = 0; v < 4; ++v) {
          const int key = kbase + t * 16 + quad * 4 + v;
          const float sv = st[t][v] + slope * (float)key - sq;
          st[t][v] = sv;
          mloc = fmaxf(mloc, sv);
        }
    }
    mloc = fmaxf(mloc, __shfl_xor(mloc, 16));
    mloc = fmaxf(mloc, __shfl_xor(mloc, 32));
    const float mn = fmaxf(m_i, mloc);
    const float alpha = __expf(m_i - mn);
    m_i = mn;
    float rsum = 0.0f;
    #pragma unroll
    for (int t = 0; t < 4; ++t) {
      bf16x4 p4;
      #pragma unroll
      for (int v = 0; v < 4; ++v) {
        const float p = __expf(st[t][v] - mn);
        rsum += p;
        p4[v] = (__bf16)p;
      }
      *(bf16x4*)&Ps[w][t >> 1][r][(t & 1) * 16 + quad * 4] = p4;
    }
    rsum += __shfl_xor(rsum, 16);
    rsum += __shfl_xor(rsum, 32);
    l_i = l_i * alpha + rsum;
    #pragma unroll
    for (int dt = 0; dt < 4; ++dt) ot[dt] *= alpha;

    #pragma unroll
    for (int kb = 0; kb < 2; ++kb) {
      const bf16x8 pf = *(const bf16x8*)&Ps[w][kb][r][quad * 8];
      #pragma unroll
      for (int dt = 0; dt < 4; ++dt) {
        const bf16x8 vf = *(const bf16x8*)&Vs[kb][dt * 16 + r][quad * 8];
        ot[dt] = __builtin_amdgcn_mfma_f32_16x16x32_bf16(vf, pf, ot[dt], 0, 0, 0);
      }
    }
    __syncthreads();
  }

  const float linv = 1.0f / l_i;
  __bf16* ob = out + (size_t)(b * SEQ + q) * D_MODEL + h * 64;
  #pragma unroll
  for (int dt = 0; dt < 4; ++dt) {
    bf16x4 o4 = { (__bf16)(ot[dt][0] * linv), (__bf16)(ot[dt][1] * linv),
                  (__bf16)(ot[dt][2] * linv), (__bf16)(ot[dt][3] * linv) };
    *(bf16x4*)(ob + dt * 16 + quad * 4) = o4;
  }
}

// ---------- driver ----------
extern "C" void kernel_launch(void* const* d_in, const int* in_sizes, int n_in,
                              void* d_out, int out_size, void* d_ws, size_t ws_size,
                              hipStream_t stream)
{
  (void)in_sizes; (void)n_in; (void)out_size;
  const float* x    = (const float*)d_in[0];
  const float* inW  = (const float*)d_in[1];
  const float* inB  = (const float*)d_in[2];
  const float* outW = (const float*)d_in[3];
  const float* outB = (const float*)d_in[4];
  const float* f1W  = (const float*)d_in[5];
  const float* f1B  = (const float*)d_in[6];
  const float* f2W  = (const float*)d_in[7];
  const float* f2B  = (const float*)d_in[8];
  const float* ln1W = (const float*)d_in[9];
  const float* ln1B = (const float*)d_in[10];
  const float* ln2W = (const float*)d_in[11];
  const float* ln2B = (const float*)d_in[12];
  const float* fnW  = (const float*)d_in[13];
  const float* fnB  = (const float*)d_in[14];

  char* ws = (char*)d_ws;
  float*  x_cur = (float*)(ws);                    // 16.78 MB fp32 residual
  __bf16* xn    = (__bf16*)(ws + 16777216);        //  8.39 MB
  __bf16* qk    = (__bf16*)(ws + 25165824);        // 16.78 MB
  __bf16* vT    = (__bf16*)(ws + 41943040);        //  8.39 MB
  __bf16* attn  = (__bf16*)(ws + 50331648);        //  8.39 MB
  __bf16* hbuf  = (__bf16*)(ws + 25165824);        // 33.55 MB, aliases qk/vT/attn (dead by FFN1)
  // bf16 weight cache (one-time convert per launch)
  __bf16* inWb  = (__bf16*)(ws + 58720256);        // 25.17 MB
  __bf16* outWb = (__bf16*)(ws + 83886080);        //  8.39 MB
  __bf16* f1Wb  = (__bf16*)(ws + 92274688);        // 33.55 MB
  __bf16* f2Wb  = (__bf16*)(ws + 125829120);       // 33.55 MB -> need 159,383,552 B
  const bool bf16w = ws_size >= (size_t)159383552;

  hipMemcpyAsync(x_cur, x, (size_t)16777216, hipMemcpyDeviceToDevice, stream);

  if (bf16w) {
    cvtw_kernel<<<dim3(12288), dim3(256), 0, stream>>>(inW,  inWb);
    cvtw_kernel<<<dim3(4096),  dim3(256), 0, stream>>>(outW, outWb);
    cvtw_kernel<<<dim3(16384), dim3(256), 0, stream>>>(f1W,  f1Wb);
    cvtw_kernel<<<dim3(16384), dim3(256), 0, stream>>>(f2W,  f2Wb);
  }

  for (int i = 0; i < 4; ++i) {
    ln_kernel<true><<<dim3(4096), dim3(256), 0, stream>>>(
        x_cur, ln1W + i * 1024, ln1B + i * 1024, xn);
    if (bf16w)
      gemm256_kernel<EPI_QKV><<<dim3(16, 12), dim3(512), 0, stream>>>(
          xn, inWb + (size_t)i * 3072 * 1024, inB + (size_t)i * 3072,
          qk, vT, 4096, 3072, 1024);
    else
      gemm_legacy_kernel<EPI_QKV, 128><<<dim3(32, 24), dim3(256), 0, stream>>>(
          xn, inW + (size_t)i * 3072 * 1024, inB + (size_t)i * 3072,
          qk, nullptr, vT, 4096, 3072, 1024);
    attn_kernel<<<dim3(32, 32), dim3(256), 0, stream>>>(qk, vT, attn);
    if (bf16w)
      gemm64_kernel<<<dim3(32, 16), dim3(256), 0, stream>>>(
          attn, outWb + (size_t)i * 1024 * 1024, outB + (size_t)i * 1024,
          x_cur, x_cur, 4096, 1024, 1024);
    else
      gemm_legacy_kernel<EPI_RES, 64><<<dim3(32, 16), dim3(256), 0, stream>>>(
          attn, outW + (size_t)i * 1024 * 1024, outB + (size_t)i * 1024,
          x_cur, x_cur, nullptr, 4096, 1024, 1024);
    ln_kernel<true><<<dim3(4096), dim3(256), 0, stream>>>(
        x_cur, ln2W + i * 1024, ln2B + i * 1024, xn);
    if (bf16w)
      gemm256_kernel<EPI_GELU><<<dim3(16, 16), dim3(512), 0, stream>>>(
          xn, f1Wb + (size_t)i * 4096 * 1024, f1B + (size_t)i * 4096,
          hbuf, nullptr, 4096, 4096, 1024);
    else
      gemm_legacy_kernel<EPI_GELU, 128><<<dim3(32, 32), dim3(256), 0, stream>>>(
          xn, f1W + (size_t)i * 4096 * 1024, f1B + (size_t)i * 4096,
          hbuf, nullptr, nullptr, 4096, 4096, 1024);
    if (bf16w)
      gemm64_kernel<<<dim3(32, 16), dim3(256), 0, stream>>>(
          hbuf, f2Wb + (size_t)i * 1024 * 4096, f2B + (size_t)i * 1024,
          x_cur, x_cur, 4096, 1024, 4096);
    else
      gemm_legacy_kernel<EPI_RES, 64><<<dim3(32, 16), dim3(256), 0, stream>>>(
          hbuf, f2W + (size_t)i * 1024 * 4096, f2B + (size_t)i * 1024,
          x_cur, x_cur, nullptr, 4096, 1024, 4096);
  }
  ln_kernel<false><<<dim3(4096), dim3(256), 0, stream>>>(x_cur, fnW, fnB, d_out);
}

// Round 7
// 1239.290 us; speedup vs baseline: 1.2059x; 1.0237x over previous
//
#include <hip/hip_runtime.h>
#include <hip/hip_bf16.h>
#include <math.h>

// ---------- types ----------
typedef __bf16 bf16x8 __attribute__((ext_vector_type(8)));
typedef __bf16 bf16x4 __attribute__((ext_vector_type(4)));
typedef float  floatx4 __attribute__((ext_vector_type(4)));

#define D_MODEL 1024
#define SEQ     2048
#define NHEAD   16
#define HD      64

__device__ __forceinline__ void async16(const void* g, void* l) {
  __builtin_amdgcn_global_load_lds((const __attribute__((address_space(1))) void*)g,
                                   (__attribute__((address_space(3))) void*)l, 16, 0, 0);
}

// ---------- weight fp32 -> bf16 convert ----------
__global__ __launch_bounds__(256)
void cvtw_kernel(const float* __restrict__ in, __bf16* __restrict__ out) {
  const size_t i = ((size_t)blockIdx.x * 256 + threadIdx.x) * 4;
  const floatx4 f = *(const floatx4*)(in + i);
  bf16x4 o = { (__bf16)f[0], (__bf16)f[1], (__bf16)f[2], (__bf16)f[3] };
  *(bf16x4*)(out + i) = o;
}

// ---------- LayerNorm: fp32 row(1024) -> bf16 (or fp32 for final) ----------
template<bool OUT_BF16>
__global__ __launch_bounds__(256)
void ln_kernel(const float* __restrict__ x, const float* __restrict__ w,
               const float* __restrict__ b, void* __restrict__ out)
{
  const int row = blockIdx.x;
  const int tid = threadIdx.x;
  const floatx4 f = *(const floatx4*)(x + (size_t)row * D_MODEL + tid * 4);
  float s = f[0] + f[1] + f[2] + f[3];
  #pragma unroll
  for (int off = 1; off < 64; off <<= 1) s += __shfl_xor(s, off);
  __shared__ float red[8];
  const int wv = tid >> 6;
  if ((tid & 63) == 0) red[wv] = s;
  __syncthreads();
  const float mu = (red[0] + red[1] + red[2] + red[3]) * (1.0f / 1024.0f);
  float d0 = f[0] - mu, d1 = f[1] - mu, d2 = f[2] - mu, d3 = f[3] - mu;
  float ss = d0 * d0 + d1 * d1 + d2 * d2 + d3 * d3;
  #pragma unroll
  for (int off = 1; off < 64; off <<= 1) ss += __shfl_xor(ss, off);
  if ((tid & 63) == 0) red[4 + wv] = ss;
  __syncthreads();
  const float rstd = rsqrtf((red[4] + red[5] + red[6] + red[7]) * (1.0f / 1024.0f) + 1e-5f);
  const floatx4 wv4 = *(const floatx4*)(w + tid * 4);
  const floatx4 bv4 = *(const floatx4*)(b + tid * 4);
  const float y0 = d0 * rstd * wv4[0] + bv4[0];
  const float y1 = d1 * rstd * wv4[1] + bv4[1];
  const float y2 = d2 * rstd * wv4[2] + bv4[2];
  const float y3 = d3 * rstd * wv4[3] + bv4[3];
  if (OUT_BF16) {
    bf16x4 o = { (__bf16)y0, (__bf16)y1, (__bf16)y2, (__bf16)y3 };
    *(bf16x4*)((__bf16*)out + (size_t)row * D_MODEL + tid * 4) = o;
  } else {
    floatx4 o = { y0, y1, y2, y3 };
    *(floatx4*)((float*)out + (size_t)row * D_MODEL + tid * 4) = o;
  }
}

#define EPI_GELU 1
#define EPI_RES  2
#define EPI_QKV  3

// ---------- GEMM128 (bf16 W): m97 structure (proven ~58us here), 128x128 tile, BK=32,
// 256 thr, ~3 blocks/CU -> inter-block overlap hides staging (m114).
// LDS epilogue (R4-validated): C staged bf16 in dead LDS, drained with bf16x8 stores
// -> full-line writes (WRITE_SIZE 78->33MB incl. vT transpose scatter).
template<int MODE>
__global__ __launch_bounds__(256, 2)
void gemm128_kernel(const __bf16* __restrict__ A, const __bf16* __restrict__ W,
                    const float* __restrict__ bias, void* out,
                    __bf16* __restrict__ vT, int M, int N, int K)
{
  __shared__ __align__(16) char smem[18432];
  __bf16 (*As)[32] = reinterpret_cast<__bf16 (*)[32]>(smem);         // [128][32] 8KB
  __bf16 (*Ws)[32] = reinterpret_cast<__bf16 (*)[32]>(smem + 8192);  // [128][32] 8KB
  const int tid = threadIdx.x;
  const int lane = tid & 63, w = tid >> 6;
  const int wr = w >> 1, wc = w & 1;
  const int quad = lane >> 4, r = lane & 15;
  const int m0 = blockIdx.x * 128, n0 = blockIdx.y * 128;

  floatx4 acc[4][4] = {};

  const __bf16* Ab = A + (size_t)m0 * K;
  const __bf16* Wb = W + (size_t)n0 * K;
  const int sr = tid >> 2, sc = (tid & 3) * 8;   // 16B chunks, lane*16 LDS-contiguous

  for (int k0 = 0; k0 < K; k0 += 32) {
    async16(Ab + (size_t)sr * K + k0 + sc, &As[sr][sc]);
    async16(Ab + (size_t)(sr + 64) * K + k0 + sc, &As[sr + 64][sc]);
    async16(Wb + (size_t)sr * K + k0 + sc, &Ws[sr][sc]);
    async16(Wb + (size_t)(sr + 64) * K + k0 + sc, &Ws[sr + 64][sc]);
    __syncthreads();
    bf16x8 af[4];
    #pragma unroll
    for (int mi = 0; mi < 4; ++mi)
      af[mi] = *(const bf16x8*)&As[wr * 64 + mi * 16 + r][quad * 8];
    #pragma unroll
    for (int ni = 0; ni < 4; ++ni) {
      const bf16x8 bf = *(const bf16x8*)&Ws[wc * 64 + ni * 16 + r][quad * 8];
      #pragma unroll
      for (int mi = 0; mi < 4; ++mi)
        acc[mi][ni] = __builtin_amdgcn_mfma_f32_16x16x32_bf16(af[mi], bf, acc[mi][ni], 0, 0, 0);
    }
    __syncthreads();
  }

  // ---------- epilogue through LDS (As/Ws dead after K-loop's final sync) ----------
  __bf16 (*Cs)[136] = reinterpret_cast<__bf16 (*)[136]>(smem);  // [64][136] row-major (17408B)
  __bf16 (*Ct)[72]  = reinterpret_cast<__bf16 (*)[72]>(smem);   // [128][72] transposed (18432B)
  const bool vblock = (MODE == EPI_QKV) && (n0 >= 2048);
  const size_t ostride = (MODE == EPI_QKV) ? (size_t)2048 : (size_t)N;

  #pragma unroll
  for (int pass = 0; pass < 2; ++pass) {
    if (wr == pass) {   // the 2 waves owning this m-half write their acc
      #pragma unroll
      for (int ni = 0; ni < 4; ++ni) {
        const int nn_l = wc * 64 + ni * 16 + r;          // 0..127
        const float bvv = bias[n0 + nn_l];
        #pragma unroll
        for (int mi = 0; mi < 4; ++mi) {
          if (vblock) {
            bf16x4 o4;
            #pragma unroll
            for (int v = 0; v < 4; ++v) o4[v] = (__bf16)(acc[mi][ni][v] + bvv);
            *(bf16x4*)&Ct[nn_l][mi * 16 + quad * 4] = o4;
          } else {
            #pragma unroll
            for (int v = 0; v < 4; ++v) {
              float val = acc[mi][ni][v] + bvv;
              if (MODE == EPI_GELU)
                val = 0.5f * val * (1.0f + erff(val * 0.70710678118654752f));
              if (MODE == EPI_QKV && (n0 + nn_l) < 1024) val *= 0.125f;  // fold 1/sqrt(HD)
              Cs[mi * 16 + quad * 4 + v][nn_l] = (__bf16)val;
            }
          }
        }
      }
    }
    __syncthreads();
    if (vblock) {
      const int c0 = n0 - 2048;
      const int bb = m0 >> 11;
      #pragma unroll
      for (int rd = 0; rd < 4; ++rd) {
        const int idx = rd * 256 + tid;                  // 128 rows x 8 chunks
        const int rn = idx >> 3, ch = idx & 7;
        const bf16x8 o = *(const bf16x8*)&Ct[rn][ch * 8];
        const int c = c0 + rn, hh = c >> 6, dd = c & 63;
        const int tt = (m0 & 2047) + pass * 64 + ch * 8;
        *(bf16x8*)(vT + ((size_t)((bb * 16 + hh) * 64 + dd)) * 2048 + tt) = o;
      }
    } else {
      #pragma unroll
      for (int rd = 0; rd < 4; ++rd) {
        const int idx = rd * 256 + tid;                  // 64 rows x 16 chunks
        const int rowm = idx >> 4, ch = idx & 15;
        const bf16x8 o = *(const bf16x8*)&Cs[rowm][ch * 8];
        const int mm = m0 + pass * 64 + rowm;
        const int nn = n0 + ch * 8;
        *(bf16x8*)((__bf16*)out + (size_t)mm * ostride + nn) = o;
      }
    }
    __syncthreads();
  }
}

// ---------- GEMM64 (bf16 W): 128x64 tile, BK=64, EPI_RES; k-halves split ----------
__global__ __launch_bounds__(256, 2)
void gemm64_kernel(const __bf16* __restrict__ A, const __bf16* __restrict__ W,
                   const float* __restrict__ bias, float* __restrict__ out,
                   const float* __restrict__ res, int M, int N, int K)
{
  __shared__ __align__(16) __bf16 As0[128][32], As1[128][32];  // 16 KB
  __shared__ __align__(16) __bf16 Ws0[64][32],  Ws1[64][32];   //  8 KB
  const int tid = threadIdx.x;
  const int lane = tid & 63, w = tid >> 6;
  const int wr = w >> 1, wc = w & 1;
  const int quad = lane >> 4, r = lane & 15;
  const int m0 = blockIdx.x * 128, n0 = blockIdx.y * 64;

  floatx4 acc[4][2] = {};

  const __bf16* Ab = A + (size_t)m0 * K;
  const __bf16* Wb = W + (size_t)n0 * K;
  const int sr = tid >> 2, sc = (tid & 3) * 8;

  for (int k0 = 0; k0 < K; k0 += 64) {
    async16(Ab + (size_t)sr * K + k0 + sc,             &As0[sr][sc]);
    async16(Ab + (size_t)(sr + 64) * K + k0 + sc,      &As0[sr + 64][sc]);
    async16(Ab + (size_t)sr * K + k0 + 32 + sc,        &As1[sr][sc]);
    async16(Ab + (size_t)(sr + 64) * K + k0 + 32 + sc, &As1[sr + 64][sc]);
    async16(Wb + (size_t)sr * K + k0 + sc,             &Ws0[sr][sc]);
    async16(Wb + (size_t)sr * K + k0 + 32 + sc,        &Ws1[sr][sc]);
    __syncthreads();
    bf16x8 af0[4], af1[4];
    #pragma unroll
    for (int mi = 0; mi < 4; ++mi) {
      af0[mi] = *(const bf16x8*)&As0[wr * 64 + mi * 16 + r][quad * 8];
      af1[mi] = *(const bf16x8*)&As1[wr * 64 + mi * 16 + r][quad * 8];
    }
    #pragma unroll
    for (int ni = 0; ni < 2; ++ni) {
      const bf16x8 b0 = *(const bf16x8*)&Ws0[wc * 32 + ni * 16 + r][quad * 8];
      const bf16x8 b1 = *(const bf16x8*)&Ws1[wc * 32 + ni * 16 + r][quad * 8];
      #pragma unroll
      for (int mi = 0; mi < 4; ++mi) {
        acc[mi][ni] = __builtin_amdgcn_mfma_f32_16x16x32_bf16(af0[mi], b0, acc[mi][ni], 0, 0, 0);
        acc[mi][ni] = __builtin_amdgcn_mfma_f32_16x16x32_bf16(af1[mi], b1, acc[mi][ni], 0, 0, 0);
      }
    }
    __syncthreads();
  }

  #pragma unroll
  for (int ni = 0; ni < 2; ++ni) {
    const int nn = n0 + wc * 32 + ni * 16 + r;
    const float bv = bias[nn];
    #pragma unroll
    for (int mi = 0; mi < 4; ++mi) {
      #pragma unroll
      for (int v = 0; v < 4; ++v) {
        const int mm = m0 + wr * 64 + mi * 16 + quad * 4 + v;
        out[(size_t)mm * N + nn] = res[(size_t)mm * N + nn] + acc[mi][ni][v] + bv;
      }
    }
  }
}

// ---------- LEGACY GEMM (fp32 W) — fallback if workspace too small ----------
template<int MODE, int NT>
__global__ __launch_bounds__(256, 2)
void gemm_legacy_kernel(const __bf16* __restrict__ A, const float* __restrict__ W,
                        const float* __restrict__ bias, void* out,
                        const float* __restrict__ res, __bf16* __restrict__ vT,
                        int M, int N, int K)
{
  __shared__ __align__(16) __bf16 As[128][32];
  __shared__ __align__(16) __bf16 Ws[NT][32];
  const int tid = threadIdx.x;
  const int lane = tid & 63, w = tid >> 6;
  const int wr = w >> 1, wc = w & 1;
  const int quad = lane >> 4, r = lane & 15;
  constexpr int NACC = NT / 32;
  const int m0 = blockIdx.x * 128, n0 = blockIdx.y * NT;
  floatx4 acc[4][NACC] = {};
  const __bf16* Ab = A + (size_t)m0 * K;
  const float*  Wb = W + (size_t)n0 * K;
  const int arow = tid >> 2, ac = (tid & 3) * 8;
  const int wrow = tid >> 3, wc4 = (tid & 7) * 4;
  for (int k0 = 0; k0 < K; k0 += 32) {
    async16(Ab + (size_t)arow * K + k0 + ac, &As[arow][ac]);
    async16(Ab + (size_t)(arow + 64) * K + k0 + ac, &As[arow + 64][ac]);
    #pragma unroll
    for (int i = 0; i < NT / 32; ++i) {
      const int rw = wrow + 32 * i;
      const floatx4 f = *(const floatx4*)(Wb + (size_t)rw * K + k0 + wc4);
      bf16x4 h4 = { (__bf16)f[0], (__bf16)f[1], (__bf16)f[2], (__bf16)f[3] };
      *(bf16x4*)&Ws[rw][wc4] = h4;
    }
    __syncthreads();
    bf16x8 af[4];
    #pragma unroll
    for (int mi = 0; mi < 4; ++mi)
      af[mi] = *(const bf16x8*)&As[wr * 64 + mi * 16 + r][quad * 8];
    #pragma unroll
    for (int ni = 0; ni < NACC; ++ni) {
      bf16x8 bf = *(const bf16x8*)&Ws[wc * (NT / 2) + ni * 16 + r][quad * 8];
      #pragma unroll
      for (int mi = 0; mi < 4; ++mi)
        acc[mi][ni] = __builtin_amdgcn_mfma_f32_16x16x32_bf16(af[mi], bf, acc[mi][ni], 0, 0, 0);
    }
    __syncthreads();
  }
  #pragma unroll
  for (int ni = 0; ni < NACC; ++ni) {
    const int nn = n0 + wc * (NT / 2) + ni * 16 + r;
    const float bv = bias[nn];
    #pragma unroll
    for (int mi = 0; mi < 4; ++mi) {
      #pragma unroll
      for (int v = 0; v < 4; ++v) {
        const int mm = m0 + wr * 64 + mi * 16 + quad * 4 + v;
        float val = acc[mi][ni][v] + bv;
        if (MODE == EPI_GELU) {
          val = 0.5f * val * (1.0f + erff(val * 0.70710678118654752f));
          ((__bf16*)out)[(size_t)mm * N + nn] = (__bf16)val;
        } else if (MODE == EPI_RES) {
          ((float*)out)[(size_t)mm * N + nn] = res[(size_t)mm * N + nn] + val;
        } else if (MODE == EPI_QKV) {
          if (nn < 2048) {
            const float sv = (nn < 1024) ? val * 0.125f : val;
            ((__bf16*)out)[(size_t)mm * 2048 + nn] = (__bf16)sv;
          } else {
            const int c = nn - 2048, hh = c >> 6, dd = c & 63;
            const int bb = mm >> 11, t = mm & 2047;
            vT[(size_t)((bb * 16 + hh) * 64 + dd) * 2048 + t] = (__bf16)val;
          }
        }
      }
    }
  }
}

// ---------- Flash attention, transposed-MFMA formulation, 64-key tiles ----------
__global__ __launch_bounds__(256, 4)
void attn_kernel(const __bf16* __restrict__ qk,  // [B*T][2048]: cols 0..1023 Q(*0.125), 1024..2047 K
                 const __bf16* __restrict__ vT,  // [(b*16+h)*64+d][2048]
                 __bf16* __restrict__ out)       // [B*T][1024]
{
  __shared__ __align__(16) __bf16 Qs[2][64][32];
  __shared__ __align__(16) __bf16 Ks[2][64][32];
  __shared__ __align__(16) __bf16 Vs[2][64][32];
  __shared__ __align__(16) __bf16 Ps[4][2][16][32];
  const int tid = threadIdx.x, lane = tid & 63, w = tid >> 6;
  const int quad = lane >> 4, r = lane & 15;
  const int bh = blockIdx.x, b = bh >> 4, h = bh & 15;
  const int yk = blockIdx.y >> 3, yj = blockIdx.y & 7;
  const int qt = (yk << 3) | ((yk & 1) ? (7 - yj) : yj);
  const int q0 = qt * 64;

  {
    const __bf16* qb = qk + ((size_t)(b * SEQ + q0)) * 2048 + h * 64;
    #pragma unroll
    for (int rd = 0; rd < 2; ++rd) {
      const int c = rd * 256 + tid, half = c >> 8, row = (c >> 2) & 63, c8 = (c & 3) * 8;
      async16(qb + (size_t)row * 2048 + half * 32 + c8, &Qs[half][row][c8]);
    }
  }
  __syncthreads();
  const bf16x8 qf0 = *(const bf16x8*)&Qs[0][w * 16 + r][quad * 8];
  const bf16x8 qf1 = *(const bf16x8*)&Qs[1][w * 16 + r][quad * 8];

  const int q = q0 + w * 16 + r;
  float m_i = -INFINITY, l_i = 0.0f;
  floatx4 ot[4] = {};
  const float slope = exp2f(-0.5f * (float)(h + 1));
  const float sq = slope * (float)q;

  const __bf16* kb0 = qk + ((size_t)(b * SEQ)) * 2048 + 1024 + h * 64;
  const __bf16* vb0 = vT + ((size_t)(bh * 64)) * 2048;

  for (int kt = 0; kt <= qt; ++kt) {
    const int kbase = kt << 6;
    #pragma unroll
    for (int rd = 0; rd < 2; ++rd) {
      const int c = rd * 256 + tid, half = c >> 8, row = (c >> 2) & 63, c8 = (c & 3) * 8;
      async16(kb0 + (size_t)(kbase + row) * 2048 + half * 32 + c8, &Ks[half][row][c8]);
    }
    #pragma unroll
    for (int rd = 0; rd < 2; ++rd) {
      const int c = rd * 256 + tid, kb = c >> 8, d = (c >> 2) & 63, c8 = (c & 3) * 8;
      async16(vb0 + (size_t)d * 2048 + kbase + kb * 32 + c8, &Vs[kb][d][c8]);
    }
    __syncthreads();

    floatx4 st[4];
    #pragma unroll
    for (int t = 0; t < 4; ++t) {
      floatx4 z = { 0.0f, 0.0f, 0.0f, 0.0f };
      const bf16x8 kf0 = *(const bf16x8*)&Ks[0][t * 16 + r][quad * 8];
      const bf16x8 kf1 = *(const bf16x8*)&Ks[1][t * 16 + r][quad * 8];
      z = __builtin_amdgcn_mfma_f32_16x16x32_bf16(kf0, qf0, z, 0, 0, 0);
      st[t] = __builtin_amdgcn_mfma_f32_16x16x32_bf16(kf1, qf1, z, 0, 0, 0);
    }
    float mloc = -INFINITY;
    if (kt == qt) {
      #pragma unroll
      for (int t = 0; t < 4; ++t)
        #pragma unroll
        for (int v = 0; v < 4; ++v) {
          const int key = kbase + t * 16 + quad * 4 + v;
          float sv = st[t][v] + slope * (float)key - sq;
          sv = (key <= q) ? sv : -INFINITY;
          st[t][v] = sv;
          mloc = fmaxf(mloc, sv);
        }
    } else {
      #pragma unroll
      for (int t = 0; t < 4; ++t)
        #pragma unroll
        for (int v = 0; v < 4; ++v) {
          const int key = kbase + t * 16 + quad * 4 + v;
          const float sv = st[t][v] + slope * (float)key - sq;
          st[t][v] = sv;
          mloc = fmaxf(mloc, sv);
        }
    }
    mloc = fmaxf(mloc, __shfl_xor(mloc, 16));
    mloc = fmaxf(mloc, __shfl_xor(mloc, 32));
    const float mn = fmaxf(m_i, mloc);
    const float alpha = __expf(m_i - mn);
    m_i = mn;
    float rsum = 0.0f;
    #pragma unroll
    for (int t = 0; t < 4; ++t) {
      bf16x4 p4;
      #pragma unroll
      for (int v = 0; v < 4; ++v) {
        const float p = __expf(st[t][v] - mn);
        rsum += p;
        p4[v] = (__bf16)p;
      }
      *(bf16x4*)&Ps[w][t >> 1][r][(t & 1) * 16 + quad * 4] = p4;
    }
    rsum += __shfl_xor(rsum, 16);
    rsum += __shfl_xor(rsum, 32);
    l_i = l_i * alpha + rsum;
    #pragma unroll
    for (int dt = 0; dt < 4; ++dt) ot[dt] *= alpha;

    #pragma unroll
    for (int kb = 0; kb < 2; ++kb) {
      const bf16x8 pf = *(const bf16x8*)&Ps[w][kb][r][quad * 8];
      #pragma unroll
      for (int dt = 0; dt < 4; ++dt) {
        const bf16x8 vf = *(const bf16x8*)&Vs[kb][dt * 16 + r][quad * 8];
        ot[dt] = __builtin_amdgcn_mfma_f32_16x16x32_bf16(vf, pf, ot[dt], 0, 0, 0);
      }
    }
    __syncthreads();
  }

  const float linv = 1.0f / l_i;
  __bf16* ob = out + (size_t)(b * SEQ + q) * D_MODEL + h * 64;
  #pragma unroll
  for (int dt = 0; dt < 4; ++dt) {
    bf16x4 o4 = { (__bf16)(ot[dt][0] * linv), (__bf16)(ot[dt][1] * linv),
                  (__bf16)(ot[dt][2] * linv), (__bf16)(ot[dt][3] * linv) };
    *(bf16x4*)(ob + dt * 16 + quad * 4) = o4;
  }
}

// ---------- driver ----------
extern "C" void kernel_launch(void* const* d_in, const int* in_sizes, int n_in,
                              void* d_out, int out_size, void* d_ws, size_t ws_size,
                              hipStream_t stream)
{
  (void)in_sizes; (void)n_in; (void)out_size;
  const float* x    = (const float*)d_in[0];
  const float* inW  = (const float*)d_in[1];
  const float* inB  = (const float*)d_in[2];
  const float* outW = (const float*)d_in[3];
  const float* outB = (const float*)d_in[4];
  const float* f1W  = (const float*)d_in[5];
  const float* f1B  = (const float*)d_in[6];
  const float* f2W  = (const float*)d_in[7];
  const float* f2B  = (const float*)d_in[8];
  const float* ln1W = (const float*)d_in[9];
  const float* ln1B = (const float*)d_in[10];
  const float* ln2W = (const float*)d_in[11];
  const float* ln2B = (const float*)d_in[12];
  const float* fnW  = (const float*)d_in[13];
  const float* fnB  = (const float*)d_in[14];

  char* ws = (char*)d_ws;
  float*  x_cur = (float*)(ws);                    // 16.78 MB fp32 residual
  __bf16* xn    = (__bf16*)(ws + 16777216);        //  8.39 MB
  __bf16* qk    = (__bf16*)(ws + 25165824);        // 16.78 MB
  __bf16* vT    = (__bf16*)(ws + 41943040);        //  8.39 MB
  __bf16* attn  = (__bf16*)(ws + 50331648);        //  8.39 MB
  __bf16* hbuf  = (__bf16*)(ws + 25165824);        // 33.55 MB, aliases qk/vT/attn (dead by FFN1)
  // bf16 weight cache (one-time convert per launch)
  __bf16* inWb  = (__bf16*)(ws + 58720256);        // 25.17 MB
  __bf16* outWb = (__bf16*)(ws + 83886080);        //  8.39 MB
  __bf16* f1Wb  = (__bf16*)(ws + 92274688);        // 33.55 MB
  __bf16* f2Wb  = (__bf16*)(ws + 125829120);       // 33.55 MB -> need 159,383,552 B
  const bool bf16w = ws_size >= (size_t)159383552;

  hipMemcpyAsync(x_cur, x, (size_t)16777216, hipMemcpyDeviceToDevice, stream);

  if (bf16w) {
    cvtw_kernel<<<dim3(12288), dim3(256), 0, stream>>>(inW,  inWb);
    cvtw_kernel<<<dim3(4096),  dim3(256), 0, stream>>>(outW, outWb);
    cvtw_kernel<<<dim3(16384), dim3(256), 0, stream>>>(f1W,  f1Wb);
    cvtw_kernel<<<dim3(16384), dim3(256), 0, stream>>>(f2W,  f2Wb);
  }

  for (int i = 0; i < 4; ++i) {
    ln_kernel<true><<<dim3(4096), dim3(256), 0, stream>>>(
        x_cur, ln1W + i * 1024, ln1B + i * 1024, xn);
    if (bf16w)
      gemm128_kernel<EPI_QKV><<<dim3(32, 24), dim3(256), 0, stream>>>(
          xn, inWb + (size_t)i * 3072 * 1024, inB + (size_t)i * 3072,
          qk, vT, 4096, 3072, 1024);
    else
      gemm_legacy_kernel<EPI_QKV, 128><<<dim3(32, 24), dim3(256), 0, stream>>>(
          xn, inW + (size_t)i * 3072 * 1024, inB + (size_t)i * 3072,
          qk, nullptr, vT, 4096, 3072, 1024);
    attn_kernel<<<dim3(32, 32), dim3(256), 0, stream>>>(qk, vT, attn);
    if (bf16w)
      gemm64_kernel<<<dim3(32, 16), dim3(256), 0, stream>>>(
          attn, outWb + (size_t)i * 1024 * 1024, outB + (size_t)i * 1024,
          x_cur, x_cur, 4096, 1024, 1024);
    else
      gemm_legacy_kernel<EPI_RES, 64><<<dim3(32, 16), dim3(256), 0, stream>>>(
          attn, outW + (size_t)i * 1024 * 1024, outB + (size_t)i * 1024,
          x_cur, x_cur, nullptr, 4096, 1024, 1024);
    ln_kernel<true><<<dim3(4096), dim3(256), 0, stream>>>(
        x_cur, ln2W + i * 1024, ln2B + i * 1024, xn);
    if (bf16w)
      gemm128_kernel<EPI_GELU><<<dim3(32, 32), dim3(256), 0, stream>>>(
          xn, f1Wb + (size_t)i * 4096 * 1024, f1B + (size_t)i * 4096,
          hbuf, nullptr, 4096, 4096, 1024);
    else
      gemm_legacy_kernel<EPI_GELU, 128><<<dim3(32, 32), dim3(256), 0, stream>>>(
          xn, f1W + (size_t)i * 4096 * 1024, f1B + (size_t)i * 4096,
          hbuf, nullptr, nullptr, 4096, 4096, 1024);
    if (bf16w)
      gemm64_kernel<<<dim3(32, 16), dim3(256), 0, stream>>>(
          hbuf, f2Wb + (size_t)i * 1024 * 4096, f2B + (size_t)i * 1024,
          x_cur, x_cur, 4096, 1024, 4096);
    else
      gemm_legacy_kernel<EPI_RES, 64><<<dim3(32, 16), dim3(256), 0, stream>>>(
          hbuf, f2W + (size_t)i * 1024 * 4096, f2B + (size_t)i * 1024,
          x_cur, x_cur, nullptr, 4096, 1024, 4096);
  }
  ln_kernel<false><<<dim3(4096), dim3(256), 0, stream>>>(x_cur, fnW, fnB, d_out);
}